// Round 5
// baseline (2152.852 us; speedup 1.0000x reference)
//
#include <hip/hip_runtime.h>
#include <math.h>

// Problem constants (fixed by setup_inputs)
#define BATCH 2
#define DIM   256
#define THW   8192            // T*H*W = 8*32*32
#define NTOK  16384           // BATCH*THW
#define KCB   8192            // codebook size
#define OUTQ  4194304         // BATCH*DIM*THW
#define CAP   2000000         // candidate buffer entries (16 MB in d_out)

typedef short short8 __attribute__((ext_vector_type(8)));
typedef float f32x4 __attribute__((ext_vector_type(4)));

// round-to-nearest-even float -> bf16 bits (no NaN/Inf in this data)
__device__ __forceinline__ unsigned short f2bf_rn(float v) {
    unsigned u = __float_as_uint(v);
    unsigned r = u + 0x7FFFu + ((u >> 16) & 1u);
    return (unsigned short)(r >> 16);
}
__device__ __forceinline__ float bf2f(unsigned short b) {
    return __uint_as_float((unsigned)b << 16);
}

// async global->LDS, 16B per lane (lds dest must be wave-uniform base + lane*16)
__device__ __forceinline__ void gl2lds16(const unsigned short* g, unsigned short* l) {
    __builtin_amdgcn_global_load_lds(
        (const __attribute__((address_space(1))) void*)g,
        (__attribute__((address_space(3))) void*)l, 16, 0, 0);
}

// ---------------------------------------------------------------------------
// Build Ahi/Alo [NTOK][256] bf16 (hi/lo split of z), zsq, zlosq (exact norms
// of the STORED vectors, for the rigorous candidate margin).
// ---------------------------------------------------------------------------
__global__ void k_buildA(const float* __restrict__ z,
                         unsigned short* __restrict__ Ahi,
                         unsigned short* __restrict__ Alo,
                         float* __restrict__ zsq, float* __restrict__ zlosq) {
    __shared__ ushort2 tile[64][65];
    __shared__ float zacc[64];
    __shared__ float lacc[64];
    int t = threadIdx.x;
    int n0 = blockIdx.x * 64;
    int b = n0 >> 13;
    int thw0 = n0 & 8191;
    if (t < 64) { zacc[t] = 0.f; lacc[t] = 0.f; }
    __syncthreads();
    int nn_r = t & 63, dg = t >> 6;
    float a1 = 0.f, a2 = 0.f;
    for (int dc = 0; dc < 256; dc += 64) {
        for (int r = 0; r < 16; ++r) {
            int dd = r * 4 + dg;
            float v = z[((size_t)(b * 256 + dc + dd)) * 8192 + thw0 + nn_r];
            unsigned short hb = f2bf_rn(v);
            float hf = bf2f(hb);
            unsigned short lb = f2bf_rn(v - hf);
            float lf = bf2f(lb);
            tile[dd][nn_r] = make_ushort2(hb, lb);
            a1 += v * v;
            a2 += lf * lf;
        }
        __syncthreads();
        int kk = t & 63, ng = t >> 6;
        for (int i2 = 0; i2 < 16; ++i2) {
            int nn = ng + i2 * 4;
            ushort2 hl = tile[kk][nn];
            size_t base = (size_t)(n0 + nn) * 256;
            Ahi[base + dc + kk] = hl.x;
            Alo[base + dc + kk] = hl.y;
        }
        __syncthreads();
    }
    atomicAdd(&zacc[nn_r], a1);
    atomicAdd(&lacc[nn_r], a2);
    __syncthreads();
    if (t < 64) { zsq[n0 + t] = zacc[t]; zlosq[n0 + t] = lacc[t]; }
}

// ---------------------------------------------------------------------------
// Build Bhi/Blo [KCB][256] bf16 from C_t [D][KCB]; csq, closq, and global
// maxima of csq/closq (for the margin) into accums[3]/accums[4].
// ---------------------------------------------------------------------------
__global__ void k_buildB(const float* __restrict__ C_t,
                         unsigned short* __restrict__ Bhi,
                         unsigned short* __restrict__ Blo,
                         float* __restrict__ csq, float* __restrict__ closq,
                         float* __restrict__ accums) {
    __shared__ ushort2 tile[64][65];
    __shared__ float kacc[64];
    __shared__ float lacc[64];
    int t = threadIdx.x;
    int k0 = blockIdx.x * 64;
    if (t < 64) { kacc[t] = 0.f; lacc[t] = 0.f; }
    __syncthreads();
    int nn_r = t & 63, dg = t >> 6;
    float a1 = 0.f, a2 = 0.f;
    for (int dc = 0; dc < 256; dc += 64) {
        for (int r = 0; r < 16; ++r) {
            int dd = r * 4 + dg;
            float v = C_t[(size_t)(dc + dd) * KCB + k0 + nn_r];
            unsigned short hb = f2bf_rn(v);
            float hf = bf2f(hb);
            unsigned short lb = f2bf_rn(v - hf);
            float lf = bf2f(lb);
            tile[dd][nn_r] = make_ushort2(hb, lb);
            a1 += v * v;
            a2 += lf * lf;
        }
        __syncthreads();
        int kk = t & 63, ng = t >> 6;
        for (int i2 = 0; i2 < 16; ++i2) {
            int nn = ng + i2 * 4;
            ushort2 hl = tile[kk][nn];
            size_t base = (size_t)(k0 + nn) * 256;
            Bhi[base + dc + kk] = hl.x;
            Blo[base + dc + kk] = hl.y;
        }
        __syncthreads();
    }
    atomicAdd(&kacc[nn_r], a1);
    atomicAdd(&lacc[nn_r], a2);
    __syncthreads();
    if (t < 64) {
        csq[k0 + t] = kacc[t];
        closq[k0 + t] = lacc[t];
        atomicMax((unsigned*)&accums[3], __float_as_uint(kacc[t]));
        atomicMax((unsigned*)&accums[4], __float_as_uint(lacc[t]));
    }
}

// ---------------------------------------------------------------------------
// Generic 32x32 tile transpose: in [rows][cols] -> out [cols][rows]
// ---------------------------------------------------------------------------
__global__ void k_transpose(const float* __restrict__ in, float* __restrict__ out,
                            int rows, int cols) {
    __shared__ float tile[32][33];
    int tx = threadIdx.x, ty = threadIdx.y;   // 32 x 8
    int x  = blockIdx.x * 32 + tx;
    int y0 = blockIdx.y * 32;
    for (int j = ty; j < 32; j += 8)
        tile[j][tx] = in[(size_t)(y0 + j) * cols + x];
    __syncthreads();
    int x2 = y0 + tx;
    int y2 = blockIdx.x * 32;
    for (int j = ty; j < 32; j += 8)
        out[(size_t)(y2 + j) * rows + x2] = tile[tx][j];
}

// ---------------------------------------------------------------------------
// MLP GEMM (double-acc): Out[m][n] = act(sum_d At[d][m]*Bt[d][n])
// ---------------------------------------------------------------------------
template <int GELU>
__global__ __launch_bounds__(512) void k_gemm_tt(const float* __restrict__ At,
                                                 const float* __restrict__ Bt,
                                                 float* __restrict__ Out,
                                                 int M, int N) {
    __shared__ float As[16][64];
    __shared__ float Bs[16][128];
    int t  = threadIdx.x;
    int ty = t >> 5;
    int tx = t & 31;
    int m0 = blockIdx.y * 64;
    int n0 = blockIdx.x * 128;
    double acc[4][4] = {};
    int dq = t >> 5;
    int lq = t & 31;
    for (int dc = 0; dc < 256; dc += 16) {
        *(float2*)&As[dq][lq * 2] = *(const float2*)&At[(size_t)(dc + dq) * M + m0 + lq * 2];
        *(float4*)&Bs[dq][lq * 4] = *(const float4*)&Bt[(size_t)(dc + dq) * N + n0 + lq * 4];
        __syncthreads();
#pragma unroll
        for (int di = 0; di < 16; ++di) {
            float4 a = *(const float4*)&As[di][ty * 4];
            float4 b = *(const float4*)&Bs[di][tx * 4];
            float av[4] = {a.x, a.y, a.z, a.w};
            float bv[4] = {b.x, b.y, b.z, b.w};
#pragma unroll
            for (int i = 0; i < 4; ++i)
#pragma unroll
                for (int j = 0; j < 4; ++j)
                    acc[i][j] += (double)av[i] * (double)bv[j];
        }
        __syncthreads();
    }
#pragma unroll
    for (int i = 0; i < 4; ++i) {
        float v[4];
#pragma unroll
        for (int j = 0; j < 4; ++j) {
            float h = (float)acc[i][j];
            if (GELU) {
                double x = (double)h;
                h = (float)(x * 0.5 * (1.0 + erf(x * 0.7071067811865475244)));
            }
            v[j] = h;
        }
        *(float4*)&Out[(size_t)(m0 + ty * 4 + i) * N + n0 + tx * 4] =
            make_float4(v[0], v[1], v[2], v[3]);
    }
}

// ---------------------------------------------------------------------------
// Phase-1: d_hi GEMM (K=256, zhi·chi only), r3 2-barrier structure (known-
// good), XOR chunk swizzle (0 conflicts). Epilogue: global per-row min via
// packed atomicMin, then candidate append with a rigorous Cauchy-Schwarz
// margin: |d_true - d_hi| <= 2.1*(||zlo||*C_k + ||z||*cl_k); margin adds the
// same bound at the (unknown) winner via Cmax/CLmax. Also sum(d_hi).
// ---------------------------------------------------------------------------
__global__ __launch_bounds__(256) void k_dist_hi(const unsigned short* __restrict__ A,
                                                 const unsigned short* __restrict__ B,
                                                 const float* __restrict__ zsq,
                                                 const float* __restrict__ csq,
                                                 const float* __restrict__ zlosq,
                                                 const float* __restrict__ closq,
                                                 unsigned long long* __restrict__ packed,
                                                 float* __restrict__ accums,
                                                 unsigned long long* __restrict__ cand) {
    __shared__ __align__(16) char smem[32768];
    unsigned short* Asm = (unsigned short*)smem;           // [128][64] bf16
    unsigned short* Bsm = (unsigned short*)(smem + 16384); // [128][64] bf16
    // epilogue aliases (valid only after the final K-loop barrier):
    float* sbd   = (float*)smem;            // [2][128]
    int*   sbk   = (int*)(smem + 1024);     // [2][128]
    float* gplus = (float*)(smem + 2048);   // [128]
    float* fA    = (float*)(smem + 2560);   // [128]  2.1*||zlo||
    float* fB    = (float*)(smem + 3072);   // [128]  2.1*||z||
    float* sred  = (float*)(smem + 3584);   // [256]

    int t = threadIdx.x;
    int lane = t & 63;
    int w = t >> 6;
    int wm = w >> 1, wn = w & 1;
    int m0 = blockIdx.x * 128;   // token tile (x fastest -> same-row blocks far apart)
    int n0 = blockIdx.y * 128;   // code tile

    int rA = w * 8 + (lane >> 3);
    int ch_l = lane & 7;
    int ch_g = ch_l ^ (lane >> 3);
    const unsigned short* gA = A + (size_t)(m0 + rA) * 256 + ch_g * 8;
    const unsigned short* gB = B + (size_t)(n0 + rA) * 256 + ch_g * 8;
    unsigned short* lA = &Asm[rA * 64 + ch_l * 8];
    unsigned short* lB = &Bsm[rA * 64 + ch_l * 8];

    f32x4 acc[4][4];
#pragma unroll
    for (int i = 0; i < 4; ++i)
#pragma unroll
        for (int j = 0; j < 4; ++j)
            acc[i][j] = f32x4{0.f, 0.f, 0.f, 0.f};

#pragma unroll
    for (int i = 0; i < 4; ++i) {
        gl2lds16(gA + (size_t)(32 * i) * 256, lA + 32 * i * 64);
        gl2lds16(gB + (size_t)(32 * i) * 256, lB + 32 * i * 64);
    }
    __syncthreads();

    int l15 = lane & 15;
    int quad = lane >> 4;
    int sw = l15 & 7;
    for (int kc = 0; kc < 4; ++kc) {
#pragma unroll
        for (int kk = 0; kk < 2; ++kk) {
            short8 a[4], b[4];
#pragma unroll
            for (int i = 0; i < 4; ++i)
                a[i] = *(const short8*)&Asm[(wm * 64 + i * 16 + l15) * 64 +
                                            (((kk * 4 + quad) ^ sw) * 8)];
#pragma unroll
            for (int j = 0; j < 4; ++j)
                b[j] = *(const short8*)&Bsm[(wn * 64 + j * 16 + l15) * 64 +
                                            (((kk * 4 + quad) ^ sw) * 8)];
#pragma unroll
            for (int i = 0; i < 4; ++i)
#pragma unroll
                for (int j = 0; j < 4; ++j)
                    acc[i][j] = __builtin_amdgcn_mfma_f32_16x16x32_bf16(a[i], b[j], acc[i][j], 0, 0, 0);
        }
        __syncthreads();
        if (kc < 3) {
            int ko = (kc + 1) * 64;
#pragma unroll
            for (int i = 0; i < 4; ++i) {
                gl2lds16(gA + (size_t)(32 * i) * 256 + ko, lA + 32 * i * 64);
                gl2lds16(gB + (size_t)(32 * i) * 256 + ko, lB + 32 * i * 64);
            }
            __syncthreads();
        }
    }

    // ----- epilogue: transform to d_hi (keep in acc regs), row-min reduce
    float M1 = sqrtf(accums[3]);   // max_k ||c_k||
    float M2 = sqrtf(accums[4]);   // max_k ||clo_k||
    float cv[4], scv[4], scl[4];
    int cols[4];
#pragma unroll
    for (int j = 0; j < 4; ++j) {
        int cloc = wn * 64 + j * 16 + l15;
        cols[j] = n0 + cloc;
        cv[j]  = csq[cols[j]];
        scv[j] = sqrtf(cv[j]);
        scl[j] = sqrtf(closq[cols[j]]);
    }
    float dsum = 0.f;
#pragma unroll
    for (int i = 0; i < 4; ++i) {
#pragma unroll
        for (int reg = 0; reg < 4; ++reg) {
            int rloc = wm * 64 + i * 16 + quad * 4 + reg;
            float zs = zsq[m0 + rloc];
            float bd = 3.4e38f;
            int   bk = 0x7fffffff;
#pragma unroll
            for (int j = 0; j < 4; ++j) {
                float dd = (zs + cv[j]) - 2.0f * acc[i][j][reg];
                acc[i][j][reg] = dd;
                dsum += dd;
                if (dd < bd || (dd == bd && cols[j] < bk)) { bd = dd; bk = cols[j]; }
            }
#pragma unroll
            for (int off = 1; off < 16; off <<= 1) {
                float od = __shfl_xor(bd, off, 64);
                int   ok = __shfl_xor(bk, off, 64);
                if (od < bd || (od == bd && ok < bk)) { bd = od; bk = ok; }
            }
            if (l15 == 0) { sbd[wn * 128 + rloc] = bd; sbk[wn * 128 + rloc] = bk; }
        }
    }
    __syncthreads();
    if (t < 128) {
        float d0 = sbd[t], d1 = sbd[128 + t];
        int   i0 = sbk[t], i1 = sbk[128 + t];
        float bd; int bk;
        if (d1 < d0 || (d1 == d0 && i1 < i0)) { bd = d1; bk = i1; }
        else                                  { bd = d0; bk = i0; }
        unsigned long long p =
            ((unsigned long long)__float_as_uint(bd) << 32) | (unsigned)bk;
        unsigned long long old = atomicMin(&packed[m0 + t], p);
        float og = __uint_as_float((unsigned)(old >> 32));
        float g  = fminf(bd, og);                 // best-so-far global row min
        float a  = 2.1f * sqrtf(zlosq[m0 + t]);
        float bb = 2.1f * sqrtf(zsq[m0 + t]);
        fA[t] = a;
        fB[t] = bb;
        gplus[t] = g + 1e-3f + a * M1 + bb * M2;  // + winner-side bound
    }
    __syncthreads();
    unsigned* cnt = (unsigned*)&accums[2];
#pragma unroll
    for (int i = 0; i < 4; ++i) {
#pragma unroll
        for (int reg = 0; reg < 4; ++reg) {
            int rloc = wm * 64 + i * 16 + quad * 4 + reg;
            float gp = gplus[rloc], a = fA[rloc], bb = fB[rloc];
#pragma unroll
            for (int j = 0; j < 4; ++j) {
                float dd = acc[i][j][reg];
                if (dd <= gp + a * scv[j] + bb * scl[j]) {
                    unsigned pos = atomicAdd(cnt, 1u);
                    if (pos < CAP)
                        cand[pos] = ((unsigned long long)__float_as_uint(dd) << 32) |
                                    (unsigned)(((m0 + rloc) << 13) | cols[j]);
                }
            }
        }
    }
    __syncthreads();
    sred[t] = dsum;
    __syncthreads();
    for (int s = 128; s > 0; s >>= 1) {
        if (t < s) sred[t] += sred[t + s];
        __syncthreads();
    }
    if (t == 0) atomicAdd(&accums[0], sred[0]);
}

// ---------------------------------------------------------------------------
// Phase-2: re-filter candidates against FINAL row min, rescore survivors
// exactly from (hi+lo) pairs, lex atomicMin into packed2. One wave/entry.
// ---------------------------------------------------------------------------
__global__ __launch_bounds__(256) void k_rescore(const unsigned long long* __restrict__ cand,
                                                 const unsigned short* __restrict__ Ahi,
                                                 const unsigned short* __restrict__ Alo,
                                                 const unsigned short* __restrict__ Bhi,
                                                 const unsigned short* __restrict__ Blo,
                                                 const float* __restrict__ zsq,
                                                 const float* __restrict__ csq,
                                                 const float* __restrict__ zlosq,
                                                 const float* __restrict__ closq,
                                                 const unsigned long long* __restrict__ packed,
                                                 unsigned long long* __restrict__ packed2,
                                                 const float* __restrict__ accums) {
    unsigned total = *(const unsigned*)&accums[2];
    if (total > CAP) total = CAP;
    float M1 = sqrtf(accums[3]);
    float M2 = sqrtf(accums[4]);
    int lane = threadIdx.x & 63;
    unsigned wv = blockIdx.x * 4 + (threadIdx.x >> 6);
    unsigned nw = gridDim.x * 4;
    for (unsigned e = wv; e < total; e += nw) {
        unsigned long long ent = cand[e];
        float dhi = __uint_as_float((unsigned)(ent >> 32));
        unsigned nk = (unsigned)ent;
        int n = (nk >> 13) & 16383;
        int k = nk & 8191;
        float g = __uint_as_float((unsigned)(packed[n] >> 32));
        float a  = 2.1f * sqrtf(zlosq[n]);
        float bb = 2.1f * sqrtf(zsq[n]);
        float marg = g + 1e-3f + a * (M1 + sqrtf(csq[k])) + bb * (M2 + sqrtf(closq[k]));
        if (dhi > marg) continue;
        ushort4 zh = *((const ushort4*)(Ahi + (size_t)n * 256) + lane);
        ushort4 zl = *((const ushort4*)(Alo + (size_t)n * 256) + lane);
        ushort4 ch = *((const ushort4*)(Bhi + (size_t)k * 256) + lane);
        ushort4 cl = *((const ushort4*)(Blo + (size_t)k * 256) + lane);
        float s = (bf2f(zh.x) + bf2f(zl.x)) * (bf2f(ch.x) + bf2f(cl.x))
                + (bf2f(zh.y) + bf2f(zl.y)) * (bf2f(ch.y) + bf2f(cl.y))
                + (bf2f(zh.z) + bf2f(zl.z)) * (bf2f(ch.z) + bf2f(cl.z))
                + (bf2f(zh.w) + bf2f(zl.w)) * (bf2f(ch.w) + bf2f(cl.w));
#pragma unroll
        for (int off = 1; off < 64; off <<= 1)
            s += __shfl_xor(s, off, 64);
        if (lane == 0) {
            float dd = (zsq[n] + csq[k]) - 2.0f * s;
            unsigned long long p =
                ((unsigned long long)__float_as_uint(dd) << 32) | (unsigned)k;
            atomicMin(&packed2[n], p);
        }
    }
}

// ---------------------------------------------------------------------------
// Unpack argmin + histogram
// ---------------------------------------------------------------------------
__global__ void k_unpack(const unsigned long long* __restrict__ packed2,
                         int* __restrict__ idx, int* __restrict__ counts) {
    int n = blockIdx.x * 256 + threadIdx.x;
    unsigned long long p = packed2[n];
    int k = (int)(p & 0xffffffffull);
    idx[n] = k;
    atomicAdd(&counts[k], 1);
}

// ---------------------------------------------------------------------------
// z_q gather (channels-first) + loss partial sums
// ---------------------------------------------------------------------------
__global__ void k_zqloss(const float* __restrict__ z, const float* __restrict__ C_t,
                         const int* __restrict__ idx, float* __restrict__ out,
                         float* __restrict__ loss_sum) {
    __shared__ float red[256];
    int bid = blockIdx.x;
    int b = bid >> 8;
    int d = bid & 255;
    int t = threadIdx.x;
    const float* crow = C_t + (size_t)d * KCB;
    const int* ib = idx + b * THW;
    size_t base = ((size_t)(b * DIM + d)) * THW;
    float lsum = 0.f;
    for (int it = 0; it < 32; ++it) {
        int thw = it * 256 + t;
        int id = ib[thw];
        float v = crow[id];
        float zz = z[base + thw];
        out[base + thw] = v;
        float df = v - zz;
        lsum += df * df;
    }
    red[t] = lsum;
    __syncthreads();
    for (int s = 128; s > 0; s >>= 1) {
        if (t < s) red[t] += red[t + s];
        __syncthreads();
    }
    if (t == 0) atomicAdd(loss_sum, red[0]);
}

// ---------------------------------------------------------------------------
// Final scalars
// ---------------------------------------------------------------------------
__global__ void k_scalars(const int* __restrict__ counts,
                          const float* __restrict__ accums,
                          float* __restrict__ out_tail) {
    __shared__ float red[256];
    int t = threadIdx.x;
    float s = 0.f;
    for (int k = t; k < KCB; k += 256) {
        float e = (float)counts[k] * (1.0f / 16384.0f);
        s += e * logf(e + 1e-10f);
    }
    red[t] = s;
    __syncthreads();
    for (int st = 128; st > 0; st >>= 1) {
        if (t < st) red[t] += red[t + st];
        __syncthreads();
    }
    if (t == 0) {
        out_tail[0] = 1.25f * accums[1] / 4194304.0f;
        out_tail[1] = expf(-red[0]);
        out_tail[2] = accums[0] / (16384.0f * 8192.0f);
    }
}

// ---------------------------------------------------------------------------
extern "C" void kernel_launch(void* const* d_in, const int* in_sizes, int n_in,
                              void* d_out, int out_size, void* d_ws, size_t ws_size,
                              hipStream_t stream) {
    const float* z     = (const float*)d_in[0];   // [2][256][8192]
    const float* emb_w = (const float*)d_in[1];   // [8192][256]
    const float* w1    = (const float*)d_in[2];   // [256][256]
    const float* w2    = (const float*)d_in[3];   // [256][256]
    float* out = (float*)d_out;

    char* w = (char*)d_ws;
    unsigned short* Ahi = (unsigned short*)(w + 0);          //  8,388,608 B
    unsigned short* Alo = (unsigned short*)(w + 8388608);    //  8,388,608 B
    float* R1    = (float*)(w + 16777216);   // emb_t, aliased by C_t (8,388,608 B)
    float* H_t   = (float*)(w + 25165824);   //  8,388,608 B
    unsigned short* Bhi = (unsigned short*)(w + 33554432);   //  4,194,304 B
    unsigned short* Blo = (unsigned short*)(w + 37748736);   //  4,194,304 B
    float* w1t   = (float*)(w + 41943040);   //    262,144 B
    float* w2t   = (float*)(w + 42205184);   //    262,144 B
    float* zsq   = (float*)(w + 42467328);   //     65,536 B
    float* csq   = (float*)(w + 42532864);   //     32,768 B
    float* zlosq = (float*)(w + 42565632);   //     65,536 B
    float* closq = (float*)(w + 42631168);   //     32,768 B
    unsigned long long* packed  = (unsigned long long*)(w + 42663936); // 131,072 B
    unsigned long long* packed2 = (unsigned long long*)(w + 42795008); // 131,072 B
    int*   idx    = (int*)(w + 42926080);    //     65,536 B
    int*   counts = (int*)(w + 42991616);    //     32,768 B
    float* accums = (float*)(w + 43024384);  // [0]dsum [1]loss [2]cnt [3]csqmax [4]closqmax

    float* emb_t = R1;
    float* C_t   = R1;                        // alias: emb_t dead after gemm#1
    // candidate buffer lives in d_out: dead before k_zqloss writes z_q
    unsigned long long* cand = (unsigned long long*)d_out;   // 16,000,000 B

    hipMemsetAsync(counts, 0, 32768 + 32, stream);           // counts + accums
    hipMemsetAsync(packed, 0xFF, 262144, stream);            // packed + packed2

    // hi/lo split of z + norms
    k_buildA<<<NTOK / 64, 256, 0, stream>>>(z, Ahi, Alo, zsq, zlosq);

    // transposes for the MLP GEMMs
    {
        dim3 blk(32, 8);
        k_transpose<<<dim3(DIM / 32, KCB / 32), blk, 0, stream>>>(emb_w, emb_t, KCB, DIM);
        k_transpose<<<dim3(DIM / 32, DIM / 32), blk, 0, stream>>>(w1, w1t, DIM, DIM);
        k_transpose<<<dim3(DIM / 32, DIM / 32), blk, 0, stream>>>(w2, w2t, DIM, DIM);
    }
    // codebook MLP: H_t = gelu(w1 @ emb^T) ; C_t = w2 @ H^T
    k_gemm_tt<1><<<dim3(KCB / 128, DIM / 64), 512, 0, stream>>>(w1t, emb_t, H_t, DIM, KCB);
    k_gemm_tt<0><<<dim3(KCB / 128, DIM / 64), 512, 0, stream>>>(w2t, H_t, C_t, DIM, KCB);
    // hi/lo split of codebook + norms + maxima
    k_buildB<<<KCB / 64, 256, 0, stream>>>(C_t, Bhi, Blo, csq, closq, accums);

    // Phase-1: d_hi GEMM + row-min + candidate append + sum(d)
    k_dist_hi<<<dim3(NTOK / 128, KCB / 128), 256, 0, stream>>>(
        Ahi, Bhi, zsq, csq, zlosq, closq, packed, accums, cand);

    // Phase-2: exact rescore of survivors
    k_rescore<<<1024, 256, 0, stream>>>(cand, Ahi, Alo, Bhi, Blo, zsq, csq,
                                        zlosq, closq, packed, packed2, accums);

    k_unpack<<<NTOK / 256, 256, 0, stream>>>(packed2, idx, counts);
    k_zqloss<<<BATCH * DIM, 256, 0, stream>>>(z, C_t, idx, out, accums + 1);
    k_scalars<<<1, 256, 0, stream>>>(counts, accums, out + OUTQ);
}

// Round 6
// 675.631 us; speedup vs baseline: 3.1864x; 3.1864x over previous
//
#include <hip/hip_runtime.h>
#include <math.h>

// Problem constants (fixed by setup_inputs)
#define BATCH 2
#define DIM   256
#define THW   8192            // T*H*W = 8*32*32
#define NTOK  16384           // BATCH*THW
#define KCB   8192            // codebook size
#define OUTQ  4194304         // BATCH*DIM*THW
#define CAP   2000000         // candidate buffer entries (16 MB in d_out)
#define SCAP  3488            // per-block LDS candidate staging capacity

typedef short short8 __attribute__((ext_vector_type(8)));
typedef float f32x4 __attribute__((ext_vector_type(4)));

// round-to-nearest-even float -> bf16 bits (no NaN/Inf in this data)
__device__ __forceinline__ unsigned short f2bf_rn(float v) {
    unsigned u = __float_as_uint(v);
    unsigned r = u + 0x7FFFu + ((u >> 16) & 1u);
    return (unsigned short)(r >> 16);
}
__device__ __forceinline__ float bf2f(unsigned short b) {
    return __uint_as_float((unsigned)b << 16);
}

// async global->LDS, 16B per lane (lds dest must be wave-uniform base + lane*16)
__device__ __forceinline__ void gl2lds16(const unsigned short* g, unsigned short* l) {
    __builtin_amdgcn_global_load_lds(
        (const __attribute__((address_space(1))) void*)g,
        (__attribute__((address_space(3))) void*)l, 16, 0, 0);
}

// ---------------------------------------------------------------------------
// Build Ahi/Alo [NTOK][256] bf16 (hi/lo split of z), zsq, zlosq (exact norms
// of the STORED vectors, for the rigorous candidate margin).
// ---------------------------------------------------------------------------
__global__ void k_buildA(const float* __restrict__ z,
                         unsigned short* __restrict__ Ahi,
                         unsigned short* __restrict__ Alo,
                         float* __restrict__ zsq, float* __restrict__ zlosq) {
    __shared__ ushort2 tile[64][65];
    __shared__ float zacc[64];
    __shared__ float lacc[64];
    int t = threadIdx.x;
    int n0 = blockIdx.x * 64;
    int b = n0 >> 13;
    int thw0 = n0 & 8191;
    if (t < 64) { zacc[t] = 0.f; lacc[t] = 0.f; }
    __syncthreads();
    int nn_r = t & 63, dg = t >> 6;
    float a1 = 0.f, a2 = 0.f;
    for (int dc = 0; dc < 256; dc += 64) {
        for (int r = 0; r < 16; ++r) {
            int dd = r * 4 + dg;
            float v = z[((size_t)(b * 256 + dc + dd)) * 8192 + thw0 + nn_r];
            unsigned short hb = f2bf_rn(v);
            float hf = bf2f(hb);
            unsigned short lb = f2bf_rn(v - hf);
            float lf = bf2f(lb);
            tile[dd][nn_r] = make_ushort2(hb, lb);
            a1 += v * v;
            a2 += lf * lf;
        }
        __syncthreads();
        int kk = t & 63, ng = t >> 6;
        for (int i2 = 0; i2 < 16; ++i2) {
            int nn = ng + i2 * 4;
            ushort2 hl = tile[kk][nn];
            size_t base = (size_t)(n0 + nn) * 256;
            Ahi[base + dc + kk] = hl.x;
            Alo[base + dc + kk] = hl.y;
        }
        __syncthreads();
    }
    atomicAdd(&zacc[nn_r], a1);
    atomicAdd(&lacc[nn_r], a2);
    __syncthreads();
    if (t < 64) { zsq[n0 + t] = zacc[t]; zlosq[n0 + t] = lacc[t]; }
}

// ---------------------------------------------------------------------------
// Build Bhi/Blo [KCB][256] bf16 from C_t [D][KCB]; csq, closq, and global
// maxima of csq/closq (for the margin) into accums[3]/accums[4].
// ---------------------------------------------------------------------------
__global__ void k_buildB(const float* __restrict__ C_t,
                         unsigned short* __restrict__ Bhi,
                         unsigned short* __restrict__ Blo,
                         float* __restrict__ csq, float* __restrict__ closq,
                         float* __restrict__ accums) {
    __shared__ ushort2 tile[64][65];
    __shared__ float kacc[64];
    __shared__ float lacc[64];
    int t = threadIdx.x;
    int k0 = blockIdx.x * 64;
    if (t < 64) { kacc[t] = 0.f; lacc[t] = 0.f; }
    __syncthreads();
    int nn_r = t & 63, dg = t >> 6;
    float a1 = 0.f, a2 = 0.f;
    for (int dc = 0; dc < 256; dc += 64) {
        for (int r = 0; r < 16; ++r) {
            int dd = r * 4 + dg;
            float v = C_t[(size_t)(dc + dd) * KCB + k0 + nn_r];
            unsigned short hb = f2bf_rn(v);
            float hf = bf2f(hb);
            unsigned short lb = f2bf_rn(v - hf);
            float lf = bf2f(lb);
            tile[dd][nn_r] = make_ushort2(hb, lb);
            a1 += v * v;
            a2 += lf * lf;
        }
        __syncthreads();
        int kk = t & 63, ng = t >> 6;
        for (int i2 = 0; i2 < 16; ++i2) {
            int nn = ng + i2 * 4;
            ushort2 hl = tile[kk][nn];
            size_t base = (size_t)(k0 + nn) * 256;
            Bhi[base + dc + kk] = hl.x;
            Blo[base + dc + kk] = hl.y;
        }
        __syncthreads();
    }
    atomicAdd(&kacc[nn_r], a1);
    atomicAdd(&lacc[nn_r], a2);
    __syncthreads();
    if (t < 64) {
        csq[k0 + t] = kacc[t];
        closq[k0 + t] = lacc[t];
        atomicMax((unsigned*)&accums[3], __float_as_uint(kacc[t]));
        atomicMax((unsigned*)&accums[4], __float_as_uint(lacc[t]));
    }
}

// ---------------------------------------------------------------------------
// Generic 32x32 tile transpose: in [rows][cols] -> out [cols][rows]
// ---------------------------------------------------------------------------
__global__ void k_transpose(const float* __restrict__ in, float* __restrict__ out,
                            int rows, int cols) {
    __shared__ float tile[32][33];
    int tx = threadIdx.x, ty = threadIdx.y;   // 32 x 8
    int x  = blockIdx.x * 32 + tx;
    int y0 = blockIdx.y * 32;
    for (int j = ty; j < 32; j += 8)
        tile[j][tx] = in[(size_t)(y0 + j) * cols + x];
    __syncthreads();
    int x2 = y0 + tx;
    int y2 = blockIdx.x * 32;
    for (int j = ty; j < 32; j += 8)
        out[(size_t)(y2 + j) * rows + x2] = tile[tx][j];
}

// ---------------------------------------------------------------------------
// MLP GEMM (double-acc): Out[m][n] = act(sum_d At[d][m]*Bt[d][n])
// ---------------------------------------------------------------------------
template <int GELU>
__global__ __launch_bounds__(512) void k_gemm_tt(const float* __restrict__ At,
                                                 const float* __restrict__ Bt,
                                                 float* __restrict__ Out,
                                                 int M, int N) {
    __shared__ float As[16][64];
    __shared__ float Bs[16][128];
    int t  = threadIdx.x;
    int ty = t >> 5;
    int tx = t & 31;
    int m0 = blockIdx.y * 64;
    int n0 = blockIdx.x * 128;
    double acc[4][4] = {};
    int dq = t >> 5;
    int lq = t & 31;
    for (int dc = 0; dc < 256; dc += 16) {
        *(float2*)&As[dq][lq * 2] = *(const float2*)&At[(size_t)(dc + dq) * M + m0 + lq * 2];
        *(float4*)&Bs[dq][lq * 4] = *(const float4*)&Bt[(size_t)(dc + dq) * N + n0 + lq * 4];
        __syncthreads();
#pragma unroll
        for (int di = 0; di < 16; ++di) {
            float4 a = *(const float4*)&As[di][ty * 4];
            float4 b = *(const float4*)&Bs[di][tx * 4];
            float av[4] = {a.x, a.y, a.z, a.w};
            float bv[4] = {b.x, b.y, b.z, b.w};
#pragma unroll
            for (int i = 0; i < 4; ++i)
#pragma unroll
                for (int j = 0; j < 4; ++j)
                    acc[i][j] += (double)av[i] * (double)bv[j];
        }
        __syncthreads();
    }
#pragma unroll
    for (int i = 0; i < 4; ++i) {
        float v[4];
#pragma unroll
        for (int j = 0; j < 4; ++j) {
            float h = (float)acc[i][j];
            if (GELU) {
                double x = (double)h;
                h = (float)(x * 0.5 * (1.0 + erf(x * 0.7071067811865475244)));
            }
            v[j] = h;
        }
        *(float4*)&Out[(size_t)(m0 + ty * 4 + i) * N + n0 + tx * 4] =
            make_float4(v[0], v[1], v[2], v[3]);
    }
}

// ---------------------------------------------------------------------------
// Phase-1: d_hi GEMM (K=256, zhi·chi only), r3 2-barrier structure, XOR chunk
// swizzle (0 conflicts). Epilogue: global per-row min via packed atomicMin,
// then candidate append with rigorous Cauchy-Schwarz margin — appends are
// STAGED IN LDS (shared-atomic counter) and flushed with ONE global
// atomicAdd per block (fixes the r5 same-address atomic storm).
// ---------------------------------------------------------------------------
__global__ __launch_bounds__(256) void k_dist_hi(const unsigned short* __restrict__ A,
                                                 const unsigned short* __restrict__ B,
                                                 const float* __restrict__ zsq,
                                                 const float* __restrict__ csq,
                                                 const float* __restrict__ zlosq,
                                                 const float* __restrict__ closq,
                                                 unsigned long long* __restrict__ packed,
                                                 float* __restrict__ accums,
                                                 unsigned long long* __restrict__ cand) {
    __shared__ __align__(16) char smem[32768];
    unsigned short* Asm = (unsigned short*)smem;           // [128][64] bf16
    unsigned short* Bsm = (unsigned short*)(smem + 16384); // [128][64] bf16
    // epilogue aliases (valid only after the final K-loop barrier):
    float* sbd   = (float*)smem;                     // [2][128]   0..1024
    int*   sbk   = (int*)(smem + 1024);              // [2][128]   1024..2048
    float* gplus = (float*)(smem + 2048);            // [128]
    float* fA    = (float*)(smem + 2560);            // [128]  2.1*||zlo||
    float* fB    = (float*)(smem + 3072);            // [128]  2.1*||z||
    float* sred  = (float*)(smem + 3584);            // [256]  3584..4608
    unsigned* scnt  = (unsigned*)(smem + 4608);      // staging counter
    unsigned* sbase = (unsigned*)(smem + 4612);      // reserved global base
    unsigned long long* scand = (unsigned long long*)(smem + 4864); // [SCAP]

    int t = threadIdx.x;
    int lane = t & 63;
    int w = t >> 6;
    int wm = w >> 1, wn = w & 1;
    int m0 = blockIdx.x * 128;   // token tile (x fastest -> same-row blocks far apart)
    int n0 = blockIdx.y * 128;   // code tile

    int rA = w * 8 + (lane >> 3);
    int ch_l = lane & 7;
    int ch_g = ch_l ^ (lane >> 3);
    const unsigned short* gA = A + (size_t)(m0 + rA) * 256 + ch_g * 8;
    const unsigned short* gB = B + (size_t)(n0 + rA) * 256 + ch_g * 8;
    unsigned short* lA = &Asm[rA * 64 + ch_l * 8];
    unsigned short* lB = &Bsm[rA * 64 + ch_l * 8];

    f32x4 acc[4][4];
#pragma unroll
    for (int i = 0; i < 4; ++i)
#pragma unroll
        for (int j = 0; j < 4; ++j)
            acc[i][j] = f32x4{0.f, 0.f, 0.f, 0.f};

#pragma unroll
    for (int i = 0; i < 4; ++i) {
        gl2lds16(gA + (size_t)(32 * i) * 256, lA + 32 * i * 64);
        gl2lds16(gB + (size_t)(32 * i) * 256, lB + 32 * i * 64);
    }
    __syncthreads();

    int l15 = lane & 15;
    int quad = lane >> 4;
    int sw = l15 & 7;
    for (int kc = 0; kc < 4; ++kc) {
#pragma unroll
        for (int kk = 0; kk < 2; ++kk) {
            short8 a[4], b[4];
#pragma unroll
            for (int i = 0; i < 4; ++i)
                a[i] = *(const short8*)&Asm[(wm * 64 + i * 16 + l15) * 64 +
                                            (((kk * 4 + quad) ^ sw) * 8)];
#pragma unroll
            for (int j = 0; j < 4; ++j)
                b[j] = *(const short8*)&Bsm[(wn * 64 + j * 16 + l15) * 64 +
                                            (((kk * 4 + quad) ^ sw) * 8)];
#pragma unroll
            for (int i = 0; i < 4; ++i)
#pragma unroll
                for (int j = 0; j < 4; ++j)
                    acc[i][j] = __builtin_amdgcn_mfma_f32_16x16x32_bf16(a[i], b[j], acc[i][j], 0, 0, 0);
        }
        __syncthreads();
        if (kc < 3) {
            int ko = (kc + 1) * 64;
#pragma unroll
            for (int i = 0; i < 4; ++i) {
                gl2lds16(gA + (size_t)(32 * i) * 256 + ko, lA + 32 * i * 64);
                gl2lds16(gB + (size_t)(32 * i) * 256 + ko, lB + 32 * i * 64);
            }
            __syncthreads();
        }
    }

    // ----- epilogue: transform to d_hi (keep in acc regs), row-min reduce
    if (t == 0) *scnt = 0;
    float M1 = sqrtf(accums[3]);   // max_k ||c_k||
    float M2 = sqrtf(accums[4]);   // max_k ||clo_k||
    float cv[4], scv[4], scl[4];
    int cols[4];
#pragma unroll
    for (int j = 0; j < 4; ++j) {
        int cloc = wn * 64 + j * 16 + l15;
        cols[j] = n0 + cloc;
        cv[j]  = csq[cols[j]];
        scv[j] = sqrtf(cv[j]);
        scl[j] = sqrtf(closq[cols[j]]);
    }
    float dsum = 0.f;
#pragma unroll
    for (int i = 0; i < 4; ++i) {
#pragma unroll
        for (int reg = 0; reg < 4; ++reg) {
            int rloc = wm * 64 + i * 16 + quad * 4 + reg;
            float zs = zsq[m0 + rloc];
            float bd = 3.4e38f;
            int   bk = 0x7fffffff;
#pragma unroll
            for (int j = 0; j < 4; ++j) {
                float dd = (zs + cv[j]) - 2.0f * acc[i][j][reg];
                acc[i][j][reg] = dd;
                dsum += dd;
                if (dd < bd || (dd == bd && cols[j] < bk)) { bd = dd; bk = cols[j]; }
            }
#pragma unroll
            for (int off = 1; off < 16; off <<= 1) {
                float od = __shfl_xor(bd, off, 64);
                int   ok = __shfl_xor(bk, off, 64);
                if (od < bd || (od == bd && ok < bk)) { bd = od; bk = ok; }
            }
            if (l15 == 0) { sbd[wn * 128 + rloc] = bd; sbk[wn * 128 + rloc] = bk; }
        }
    }
    __syncthreads();
    if (t < 128) {
        float d0 = sbd[t], d1 = sbd[128 + t];
        int   i0 = sbk[t], i1 = sbk[128 + t];
        float bd; int bk;
        if (d1 < d0 || (d1 == d0 && i1 < i0)) { bd = d1; bk = i1; }
        else                                  { bd = d0; bk = i0; }
        unsigned long long p =
            ((unsigned long long)__float_as_uint(bd) << 32) | (unsigned)bk;
        unsigned long long old = atomicMin(&packed[m0 + t], p);
        float og = __uint_as_float((unsigned)(old >> 32));
        float g  = fminf(bd, og);                 // best-so-far global row min
        float a  = 2.1f * sqrtf(zlosq[m0 + t]);
        float bb = 2.1f * sqrtf(zsq[m0 + t]);
        fA[t] = a;
        fB[t] = bb;
        gplus[t] = g + 1e-3f + a * M1 + bb * M2;  // + winner-side bound
    }
    __syncthreads();
    unsigned* cnt = (unsigned*)&accums[2];
#pragma unroll
    for (int i = 0; i < 4; ++i) {
#pragma unroll
        for (int reg = 0; reg < 4; ++reg) {
            int rloc = wm * 64 + i * 16 + quad * 4 + reg;
            float gp = gplus[rloc], a = fA[rloc], bb = fB[rloc];
#pragma unroll
            for (int j = 0; j < 4; ++j) {
                float dd = acc[i][j][reg];
                if (dd <= gp + a * scv[j] + bb * scl[j]) {
                    unsigned long long entry =
                        ((unsigned long long)__float_as_uint(dd) << 32) |
                        (unsigned)(((m0 + rloc) << 13) | cols[j]);
                    unsigned p = atomicAdd(scnt, 1u);        // LDS atomic
                    if (p < SCAP) scand[p] = entry;
                    else {                                   // rare overflow
                        unsigned gp2 = atomicAdd(cnt, 1u);
                        if (gp2 < CAP) cand[gp2] = entry;
                    }
                }
            }
        }
    }
    __syncthreads();
    // flush staged candidates: ONE global atomicAdd per block
    if (t == 0) {
        unsigned m = *scnt;
        if (m > SCAP) m = SCAP;
        *scnt = m;
        *sbase = atomicAdd(cnt, m);
    }
    __syncthreads();
    {
        unsigned m = *scnt, b0 = *sbase;
        for (unsigned u = t; u < m; u += 256)
            if (b0 + u < CAP) cand[b0 + u] = scand[u];
    }
    sred[t] = dsum;
    __syncthreads();
    for (int s = 128; s > 0; s >>= 1) {
        if (t < s) sred[t] += sred[t + s];
        __syncthreads();
    }
    if (t == 0) atomicAdd(&accums[0], sred[0]);
}

// ---------------------------------------------------------------------------
// Phase-2: re-filter candidates against FINAL row min, rescore survivors
// exactly from (hi+lo) pairs, lex atomicMin into packed2. One wave/entry.
// ---------------------------------------------------------------------------
__global__ __launch_bounds__(256) void k_rescore(const unsigned long long* __restrict__ cand,
                                                 const unsigned short* __restrict__ Ahi,
                                                 const unsigned short* __restrict__ Alo,
                                                 const unsigned short* __restrict__ Bhi,
                                                 const unsigned short* __restrict__ Blo,
                                                 const float* __restrict__ zsq,
                                                 const float* __restrict__ csq,
                                                 const float* __restrict__ zlosq,
                                                 const float* __restrict__ closq,
                                                 const unsigned long long* __restrict__ packed,
                                                 unsigned long long* __restrict__ packed2,
                                                 const float* __restrict__ accums) {
    unsigned total = *(const unsigned*)&accums[2];
    if (total > CAP) total = CAP;
    float M1 = sqrtf(accums[3]);
    float M2 = sqrtf(accums[4]);
    int lane = threadIdx.x & 63;
    unsigned wv = blockIdx.x * 4 + (threadIdx.x >> 6);
    unsigned nw = gridDim.x * 4;
    for (unsigned e = wv; e < total; e += nw) {
        unsigned long long ent = cand[e];
        float dhi = __uint_as_float((unsigned)(ent >> 32));
        unsigned nk = (unsigned)ent;
        int n = (nk >> 13) & 16383;
        int k = nk & 8191;
        float g = __uint_as_float((unsigned)(packed[n] >> 32));
        float a  = 2.1f * sqrtf(zlosq[n]);
        float bb = 2.1f * sqrtf(zsq[n]);
        float marg = g + 1e-3f + a * (M1 + sqrtf(csq[k])) + bb * (M2 + sqrtf(closq[k]));
        if (dhi > marg) continue;
        ushort4 zh = *((const ushort4*)(Ahi + (size_t)n * 256) + lane);
        ushort4 zl = *((const ushort4*)(Alo + (size_t)n * 256) + lane);
        ushort4 ch = *((const ushort4*)(Bhi + (size_t)k * 256) + lane);
        ushort4 cl = *((const ushort4*)(Blo + (size_t)k * 256) + lane);
        float s = (bf2f(zh.x) + bf2f(zl.x)) * (bf2f(ch.x) + bf2f(cl.x))
                + (bf2f(zh.y) + bf2f(zl.y)) * (bf2f(ch.y) + bf2f(cl.y))
                + (bf2f(zh.z) + bf2f(zl.z)) * (bf2f(ch.z) + bf2f(cl.z))
                + (bf2f(zh.w) + bf2f(zl.w)) * (bf2f(ch.w) + bf2f(cl.w));
#pragma unroll
        for (int off = 1; off < 64; off <<= 1)
            s += __shfl_xor(s, off, 64);
        if (lane == 0) {
            float dd = (zsq[n] + csq[k]) - 2.0f * s;
            unsigned long long p =
                ((unsigned long long)__float_as_uint(dd) << 32) | (unsigned)k;
            atomicMin(&packed2[n], p);
        }
    }
}

// ---------------------------------------------------------------------------
// Unpack argmin + histogram
// ---------------------------------------------------------------------------
__global__ void k_unpack(const unsigned long long* __restrict__ packed2,
                         int* __restrict__ idx, int* __restrict__ counts) {
    int n = blockIdx.x * 256 + threadIdx.x;
    unsigned long long p = packed2[n];
    int k = (int)(p & 0xffffffffull);
    idx[n] = k;
    atomicAdd(&counts[k], 1);
}

// ---------------------------------------------------------------------------
// z_q gather (channels-first) + loss partial sums
// ---------------------------------------------------------------------------
__global__ void k_zqloss(const float* __restrict__ z, const float* __restrict__ C_t,
                         const int* __restrict__ idx, float* __restrict__ out,
                         float* __restrict__ loss_sum) {
    __shared__ float red[256];
    int bid = blockIdx.x;
    int b = bid >> 8;
    int d = bid & 255;
    int t = threadIdx.x;
    const float* crow = C_t + (size_t)d * KCB;
    const int* ib = idx + b * THW;
    size_t base = ((size_t)(b * DIM + d)) * THW;
    float lsum = 0.f;
    for (int it = 0; it < 32; ++it) {
        int thw = it * 256 + t;
        int id = ib[thw];
        float v = crow[id];
        float zz = z[base + thw];
        out[base + thw] = v;
        float df = v - zz;
        lsum += df * df;
    }
    red[t] = lsum;
    __syncthreads();
    for (int s = 128; s > 0; s >>= 1) {
        if (t < s) red[t] += red[t + s];
        __syncthreads();
    }
    if (t == 0) atomicAdd(loss_sum, red[0]);
}

// ---------------------------------------------------------------------------
// Final scalars
// ---------------------------------------------------------------------------
__global__ void k_scalars(const int* __restrict__ counts,
                          const float* __restrict__ accums,
                          float* __restrict__ out_tail) {
    __shared__ float red[256];
    int t = threadIdx.x;
    float s = 0.f;
    for (int k = t; k < KCB; k += 256) {
        float e = (float)counts[k] * (1.0f / 16384.0f);
        s += e * logf(e + 1e-10f);
    }
    red[t] = s;
    __syncthreads();
    for (int st = 128; st > 0; st >>= 1) {
        if (t < st) red[t] += red[t + st];
        __syncthreads();
    }
    if (t == 0) {
        out_tail[0] = 1.25f * accums[1] / 4194304.0f;
        out_tail[1] = expf(-red[0]);
        out_tail[2] = accums[0] / (16384.0f * 8192.0f);
    }
}

// ---------------------------------------------------------------------------
extern "C" void kernel_launch(void* const* d_in, const int* in_sizes, int n_in,
                              void* d_out, int out_size, void* d_ws, size_t ws_size,
                              hipStream_t stream) {
    const float* z     = (const float*)d_in[0];   // [2][256][8192]
    const float* emb_w = (const float*)d_in[1];   // [8192][256]
    const float* w1    = (const float*)d_in[2];   // [256][256]
    const float* w2    = (const float*)d_in[3];   // [256][256]
    float* out = (float*)d_out;

    char* w = (char*)d_ws;
    unsigned short* Ahi = (unsigned short*)(w + 0);          //  8,388,608 B
    unsigned short* Alo = (unsigned short*)(w + 8388608);    //  8,388,608 B
    float* R1    = (float*)(w + 16777216);   // emb_t, aliased by C_t (8,388,608 B)
    float* H_t   = (float*)(w + 25165824);   //  8,388,608 B
    unsigned short* Bhi = (unsigned short*)(w + 33554432);   //  4,194,304 B
    unsigned short* Blo = (unsigned short*)(w + 37748736);   //  4,194,304 B
    float* w1t   = (float*)(w + 41943040);   //    262,144 B
    float* w2t   = (float*)(w + 42205184);   //    262,144 B
    float* zsq   = (float*)(w + 42467328);   //     65,536 B
    float* csq   = (float*)(w + 42532864);   //     32,768 B
    float* zlosq = (float*)(w + 42565632);   //     65,536 B
    float* closq = (float*)(w + 42631168);   //     32,768 B
    unsigned long long* packed  = (unsigned long long*)(w + 42663936); // 131,072 B
    unsigned long long* packed2 = (unsigned long long*)(w + 42795008); // 131,072 B
    int*   idx    = (int*)(w + 42926080);    //     65,536 B
    int*   counts = (int*)(w + 42991616);    //     32,768 B
    float* accums = (float*)(w + 43024384);  // [0]dsum [1]loss [2]cnt [3]csqmax [4]closqmax

    float* emb_t = R1;
    float* C_t   = R1;                        // alias: emb_t dead after gemm#1
    // candidate buffer lives in d_out: dead before k_zqloss writes z_q
    unsigned long long* cand = (unsigned long long*)d_out;   // 16,000,000 B

    hipMemsetAsync(counts, 0, 32768 + 32, stream);           // counts + accums
    hipMemsetAsync(packed, 0xFF, 262144, stream);            // packed + packed2

    // hi/lo split of z + norms
    k_buildA<<<NTOK / 64, 256, 0, stream>>>(z, Ahi, Alo, zsq, zlosq);

    // transposes for the MLP GEMMs
    {
        dim3 blk(32, 8);
        k_transpose<<<dim3(DIM / 32, KCB / 32), blk, 0, stream>>>(emb_w, emb_t, KCB, DIM);
        k_transpose<<<dim3(DIM / 32, DIM / 32), blk, 0, stream>>>(w1, w1t, DIM, DIM);
        k_transpose<<<dim3(DIM / 32, DIM / 32), blk, 0, stream>>>(w2, w2t, DIM, DIM);
    }
    // codebook MLP: H_t = gelu(w1 @ emb^T) ; C_t = w2 @ H^T
    k_gemm_tt<1><<<dim3(KCB / 128, DIM / 64), 512, 0, stream>>>(w1t, emb_t, H_t, DIM, KCB);
    k_gemm_tt<0><<<dim3(KCB / 128, DIM / 64), 512, 0, stream>>>(w2t, H_t, C_t, DIM, KCB);
    // hi/lo split of codebook + norms + maxima
    k_buildB<<<KCB / 64, 256, 0, stream>>>(C_t, Bhi, Blo, csq, closq, accums);

    // Phase-1: d_hi GEMM + row-min + candidate append + sum(d)
    k_dist_hi<<<dim3(NTOK / 128, KCB / 128), 256, 0, stream>>>(
        Ahi, Bhi, zsq, csq, zlosq, closq, packed, accums, cand);

    // Phase-2: exact rescore of survivors
    k_rescore<<<1024, 256, 0, stream>>>(cand, Ahi, Alo, Bhi, Blo, zsq, csq,
                                        zlosq, closq, packed, packed2, accums);

    k_unpack<<<NTOK / 256, 256, 0, stream>>>(packed2, idx, counts);
    k_zqloss<<<BATCH * DIM, 256, 0, stream>>>(z, C_t, idx, out, accums + 1);
    k_scalars<<<1, 256, 0, stream>>>(counts, accums, out + OUTQ);
}

// Round 7
// 609.271 us; speedup vs baseline: 3.5335x; 1.1089x over previous
//
#include <hip/hip_runtime.h>
#include <math.h>

// Problem constants (fixed by setup_inputs)
#define BATCH 2
#define DIM   256
#define THW   8192            // T*H*W = 8*32*32
#define NTOK  16384           // BATCH*THW
#define KCB   8192            // codebook size
#define OUTQ  4194304         // BATCH*DIM*THW
#define CAP   2000000         // candidate buffer entries (16 MB in d_out)
#define SCAP  3772            // per-block LDS candidate staging capacity

typedef short short8 __attribute__((ext_vector_type(8)));
typedef float f32x4 __attribute__((ext_vector_type(4)));

// round-to-nearest-even float -> bf16 bits (no NaN/Inf in this data)
__device__ __forceinline__ unsigned short f2bf_rn(float v) {
    unsigned u = __float_as_uint(v);
    unsigned r = u + 0x7FFFu + ((u >> 16) & 1u);
    return (unsigned short)(r >> 16);
}
__device__ __forceinline__ float bf2f(unsigned short b) {
    return __uint_as_float((unsigned)b << 16);
}

// async global->LDS, 16B per lane (lds dest must be wave-uniform base + lane*16)
__device__ __forceinline__ void gl2lds16(const unsigned short* g, unsigned short* l) {
    __builtin_amdgcn_global_load_lds(
        (const __attribute__((address_space(1))) void*)g,
        (__attribute__((address_space(3))) void*)l, 16, 0, 0);
}

// ---------------------------------------------------------------------------
// Build Ahi/Alo [NTOK][256] bf16 (hi/lo split of z), zsq, zlosq (exact norms
// of the STORED vectors, for the rigorous candidate margin).
// ---------------------------------------------------------------------------
__global__ void k_buildA(const float* __restrict__ z,
                         unsigned short* __restrict__ Ahi,
                         unsigned short* __restrict__ Alo,
                         float* __restrict__ zsq, float* __restrict__ zlosq) {
    __shared__ ushort2 tile[64][65];
    __shared__ float zacc[64];
    __shared__ float lacc[64];
    int t = threadIdx.x;
    int n0 = blockIdx.x * 64;
    int b = n0 >> 13;
    int thw0 = n0 & 8191;
    if (t < 64) { zacc[t] = 0.f; lacc[t] = 0.f; }
    __syncthreads();
    int nn_r = t & 63, dg = t >> 6;
    float a1 = 0.f, a2 = 0.f;
    for (int dc = 0; dc < 256; dc += 64) {
        for (int r = 0; r < 16; ++r) {
            int dd = r * 4 + dg;
            float v = z[((size_t)(b * 256 + dc + dd)) * 8192 + thw0 + nn_r];
            unsigned short hb = f2bf_rn(v);
            float hf = bf2f(hb);
            unsigned short lb = f2bf_rn(v - hf);
            float lf = bf2f(lb);
            tile[dd][nn_r] = make_ushort2(hb, lb);
            a1 += v * v;
            a2 += lf * lf;
        }
        __syncthreads();
        int kk = t & 63, ng = t >> 6;
        for (int i2 = 0; i2 < 16; ++i2) {
            int nn = ng + i2 * 4;
            ushort2 hl = tile[kk][nn];
            size_t base = (size_t)(n0 + nn) * 256;
            Ahi[base + dc + kk] = hl.x;
            Alo[base + dc + kk] = hl.y;
        }
        __syncthreads();
    }
    atomicAdd(&zacc[nn_r], a1);
    atomicAdd(&lacc[nn_r], a2);
    __syncthreads();
    if (t < 64) { zsq[n0 + t] = zacc[t]; zlosq[n0 + t] = lacc[t]; }
}

// ---------------------------------------------------------------------------
// Build Bhi/Blo [KCB][256] bf16 from C_t [D][KCB]; csq, closq, and global
// maxima of csq/closq (for the margin) into accums[3]/accums[4].
// ---------------------------------------------------------------------------
__global__ void k_buildB(const float* __restrict__ C_t,
                         unsigned short* __restrict__ Bhi,
                         unsigned short* __restrict__ Blo,
                         float* __restrict__ csq, float* __restrict__ closq,
                         float* __restrict__ accums) {
    __shared__ ushort2 tile[64][65];
    __shared__ float kacc[64];
    __shared__ float lacc[64];
    int t = threadIdx.x;
    int k0 = blockIdx.x * 64;
    if (t < 64) { kacc[t] = 0.f; lacc[t] = 0.f; }
    __syncthreads();
    int nn_r = t & 63, dg = t >> 6;
    float a1 = 0.f, a2 = 0.f;
    for (int dc = 0; dc < 256; dc += 64) {
        for (int r = 0; r < 16; ++r) {
            int dd = r * 4 + dg;
            float v = C_t[(size_t)(dc + dd) * KCB + k0 + nn_r];
            unsigned short hb = f2bf_rn(v);
            float hf = bf2f(hb);
            unsigned short lb = f2bf_rn(v - hf);
            float lf = bf2f(lb);
            tile[dd][nn_r] = make_ushort2(hb, lb);
            a1 += v * v;
            a2 += lf * lf;
        }
        __syncthreads();
        int kk = t & 63, ng = t >> 6;
        for (int i2 = 0; i2 < 16; ++i2) {
            int nn = ng + i2 * 4;
            ushort2 hl = tile[kk][nn];
            size_t base = (size_t)(k0 + nn) * 256;
            Bhi[base + dc + kk] = hl.x;
            Blo[base + dc + kk] = hl.y;
        }
        __syncthreads();
    }
    atomicAdd(&kacc[nn_r], a1);
    atomicAdd(&lacc[nn_r], a2);
    __syncthreads();
    if (t < 64) {
        csq[k0 + t] = kacc[t];
        closq[k0 + t] = lacc[t];
        atomicMax((unsigned*)&accums[3], __float_as_uint(kacc[t]));
        atomicMax((unsigned*)&accums[4], __float_as_uint(lacc[t]));
    }
}

// ---------------------------------------------------------------------------
// Generic 32x32 tile transpose: in [rows][cols] -> out [cols][rows]
// ---------------------------------------------------------------------------
__global__ void k_transpose(const float* __restrict__ in, float* __restrict__ out,
                            int rows, int cols) {
    __shared__ float tile[32][33];
    int tx = threadIdx.x, ty = threadIdx.y;   // 32 x 8
    int x  = blockIdx.x * 32 + tx;
    int y0 = blockIdx.y * 32;
    for (int j = ty; j < 32; j += 8)
        tile[j][tx] = in[(size_t)(y0 + j) * cols + x];
    __syncthreads();
    int x2 = y0 + tx;
    int y2 = blockIdx.x * 32;
    for (int j = ty; j < 32; j += 8)
        out[(size_t)(y2 + j) * rows + x2] = tile[tx][j];
}

// ---------------------------------------------------------------------------
// MLP GEMM (double-acc): Out[m][n] = act(sum_d At[d][m]*Bt[d][n])
// ---------------------------------------------------------------------------
template <int GELU>
__global__ __launch_bounds__(512) void k_gemm_tt(const float* __restrict__ At,
                                                 const float* __restrict__ Bt,
                                                 float* __restrict__ Out,
                                                 int M, int N) {
    __shared__ float As[16][64];
    __shared__ float Bs[16][128];
    int t  = threadIdx.x;
    int ty = t >> 5;
    int tx = t & 31;
    int m0 = blockIdx.y * 64;
    int n0 = blockIdx.x * 128;
    double acc[4][4] = {};
    int dq = t >> 5;
    int lq = t & 31;
    for (int dc = 0; dc < 256; dc += 16) {
        *(float2*)&As[dq][lq * 2] = *(const float2*)&At[(size_t)(dc + dq) * M + m0 + lq * 2];
        *(float4*)&Bs[dq][lq * 4] = *(const float4*)&Bt[(size_t)(dc + dq) * N + n0 + lq * 4];
        __syncthreads();
#pragma unroll
        for (int di = 0; di < 16; ++di) {
            float4 a = *(const float4*)&As[di][ty * 4];
            float4 b = *(const float4*)&Bs[di][tx * 4];
            float av[4] = {a.x, a.y, a.z, a.w};
            float bv[4] = {b.x, b.y, b.z, b.w};
#pragma unroll
            for (int i = 0; i < 4; ++i)
#pragma unroll
                for (int j = 0; j < 4; ++j)
                    acc[i][j] += (double)av[i] * (double)bv[j];
        }
        __syncthreads();
    }
#pragma unroll
    for (int i = 0; i < 4; ++i) {
        float v[4];
#pragma unroll
        for (int j = 0; j < 4; ++j) {
            float h = (float)acc[i][j];
            if (GELU) {
                double x = (double)h;
                h = (float)(x * 0.5 * (1.0 + erf(x * 0.7071067811865475244)));
            }
            v[j] = h;
        }
        *(float4*)&Out[(size_t)(m0 + ty * 4 + i) * N + n0 + tx * 4] =
            make_float4(v[0], v[1], v[2], v[3]);
    }
}

// ---------------------------------------------------------------------------
// Phase-1: d_hi GEMM (K=256, zhi·chi only), r3 2-barrier structure, XOR chunk
// swizzle (0 conflicts). FUSED epilogue (r7): single pass does transform,
// row-min shuffle reduce, and ballot-guarded candidate append using a relaxed
// LOAD of the running global min (fire-and-forget atomicMin afterwards — no
// RMW-return dependency). Margin math identical to r5/r6 (stale min is an
// upper bound -> filter only loosens, winner provably retained).
// ---------------------------------------------------------------------------
__global__ __launch_bounds__(256) void k_dist_hi(const unsigned short* __restrict__ A,
                                                 const unsigned short* __restrict__ B,
                                                 const float* __restrict__ zsq,
                                                 const float* __restrict__ csq,
                                                 const float* __restrict__ zlosq,
                                                 const float* __restrict__ closq,
                                                 unsigned long long* __restrict__ packed,
                                                 float* __restrict__ accums,
                                                 unsigned long long* __restrict__ cand) {
    __shared__ __align__(16) char smem[32768];
    unsigned short* Asm = (unsigned short*)smem;           // [128][64] bf16
    unsigned short* Bsm = (unsigned short*)(smem + 16384); // [128][64] bf16
    // epilogue aliases (valid only after the final K-loop barrier):
    float* sbd     = (float*)smem;                   // [2][128]   0..1024
    int*   sbk     = (int*)(smem + 1024);            // [2][128]   1024..2048
    float* gprev_s = (float*)(smem + 2048);          // [128]      2048..2560
    float* swred   = (float*)(smem + 2560);          // [4]
    unsigned* scnt  = (unsigned*)(smem + 2576);
    unsigned* sbase = (unsigned*)(smem + 2580);
    unsigned long long* scand = (unsigned long long*)(smem + 2592); // [SCAP]

    int t = threadIdx.x;
    int lane = t & 63;
    int w = t >> 6;
    int wm = w >> 1, wn = w & 1;
    int m0 = blockIdx.x * 128;   // token tile (x fastest -> same-row blocks far apart)
    int n0 = blockIdx.y * 128;   // code tile

    int rA = w * 8 + (lane >> 3);
    int ch_l = lane & 7;
    int ch_g = ch_l ^ (lane >> 3);
    const unsigned short* gA = A + (size_t)(m0 + rA) * 256 + ch_g * 8;
    const unsigned short* gB = B + (size_t)(n0 + rA) * 256 + ch_g * 8;
    unsigned short* lA = &Asm[rA * 64 + ch_l * 8];
    unsigned short* lB = &Bsm[rA * 64 + ch_l * 8];

    int l15 = lane & 15;
    int quad = lane >> 4;
    int sw = l15 & 7;

    // hoisted epilogue constants (off the contended accums line, overlap K-loop)
    float M1 = sqrtf(accums[3]);   // max_k ||c_k||
    float M2 = sqrtf(accums[4]);   // max_k ||clo_k||
    float cv[4], scv[4], scl[4];
    int cols[4];
#pragma unroll
    for (int j = 0; j < 4; ++j) {
        int cloc = wn * 64 + j * 16 + l15;
        cols[j] = n0 + cloc;
        cv[j]  = csq[cols[j]];
        scv[j] = sqrtf(cv[j]);
        scl[j] = sqrtf(closq[cols[j]]);
    }

    f32x4 acc[4][4];
#pragma unroll
    for (int i = 0; i < 4; ++i)
#pragma unroll
        for (int j = 0; j < 4; ++j)
            acc[i][j] = f32x4{0.f, 0.f, 0.f, 0.f};

#pragma unroll
    for (int i = 0; i < 4; ++i) {
        gl2lds16(gA + (size_t)(32 * i) * 256, lA + 32 * i * 64);
        gl2lds16(gB + (size_t)(32 * i) * 256, lB + 32 * i * 64);
    }
    __syncthreads();

    for (int kc = 0; kc < 4; ++kc) {
#pragma unroll
        for (int kk = 0; kk < 2; ++kk) {
            short8 a[4], b[4];
#pragma unroll
            for (int i = 0; i < 4; ++i)
                a[i] = *(const short8*)&Asm[(wm * 64 + i * 16 + l15) * 64 +
                                            (((kk * 4 + quad) ^ sw) * 8)];
#pragma unroll
            for (int j = 0; j < 4; ++j)
                b[j] = *(const short8*)&Bsm[(wn * 64 + j * 16 + l15) * 64 +
                                            (((kk * 4 + quad) ^ sw) * 8)];
#pragma unroll
            for (int i = 0; i < 4; ++i)
#pragma unroll
                for (int j = 0; j < 4; ++j)
                    acc[i][j] = __builtin_amdgcn_mfma_f32_16x16x32_bf16(a[i], b[j], acc[i][j], 0, 0, 0);
        }
        __syncthreads();
        if (kc < 3) {
            int ko = (kc + 1) * 64;
#pragma unroll
            for (int i = 0; i < 4; ++i) {
                gl2lds16(gA + (size_t)(32 * i) * 256 + ko, lA + 32 * i * 64);
                gl2lds16(gB + (size_t)(32 * i) * 256 + ko, lB + 32 * i * 64);
            }
            __syncthreads();
        }
    }

    // ----- fused epilogue -----
    if (t == 0) *scnt = 0;
    if (t < 128) {
        // relaxed load of current global row-min (hi word of packed); any
        // observed value is an upper bound (atomicMin is monotone) -> correct.
        const unsigned* hp = (const unsigned*)&packed[m0 + t];
        unsigned g32 = __atomic_load_n(hp + 1, __ATOMIC_RELAXED);
        gprev_s[t] = __uint_as_float(g32);
    }
    __syncthreads();

    unsigned* cnt = (unsigned*)&accums[2];
    float dsum = 0.f;
#pragma unroll
    for (int i = 0; i < 4; ++i) {
#pragma unroll
        for (int reg = 0; reg < 4; ++reg) {
            int rloc = wm * 64 + i * 16 + quad * 4 + reg;
            float zs = zsq[m0 + rloc];
            float dv[4];
            float bd = 3.4e38f;
            int   bk = 0x7fffffff;
#pragma unroll
            for (int j = 0; j < 4; ++j) {
                float dd = (zs + cv[j]) - 2.0f * acc[i][j][reg];
                dv[j] = dd;
                dsum += dd;
                if (dd < bd || (dd == bd && cols[j] < bk)) { bd = dd; bk = cols[j]; }
            }
#pragma unroll
            for (int off = 1; off < 16; off <<= 1) {
                float od = __shfl_xor(bd, off, 64);
                int   ok = __shfl_xor(bk, off, 64);
                if (od < bd || (od == bd && ok < bk)) { bd = od; bk = ok; }
            }
            if (l15 == 0) { sbd[wn * 128 + rloc] = bd; sbk[wn * 128 + rloc] = bk; }
            // candidate filter, fused (dv still in regs, bd fresh)
            float g  = fminf(bd, gprev_s[rloc]);
            float a  = 2.1f * sqrtf(zlosq[m0 + rloc]);
            float bb = 2.1f * sqrtf(zs);
            float gp = g + 1e-3f + a * M1 + bb * M2;
            bool p0 = dv[0] <= gp + a * scv[0] + bb * scl[0];
            bool p1 = dv[1] <= gp + a * scv[1] + bb * scl[1];
            bool p2 = dv[2] <= gp + a * scv[2] + bb * scl[2];
            bool p3 = dv[3] <= gp + a * scv[3] + bb * scl[3];
            if (__ballot(p0 | p1 | p2 | p3)) {     // wave-uniform skip (common)
                unsigned rbits = (unsigned)((m0 + rloc) << 13);
#pragma unroll
                for (int j = 0; j < 4; ++j) {
                    bool p = (j == 0) ? p0 : (j == 1) ? p1 : (j == 2) ? p2 : p3;
                    if (p) {
                        unsigned long long entry =
                            ((unsigned long long)__float_as_uint(dv[j]) << 32) |
                            (rbits | (unsigned)cols[j]);
                        unsigned pos = atomicAdd(scnt, 1u);
                        if (pos < SCAP) scand[pos] = entry;
                        else {
                            unsigned gp2 = atomicAdd(cnt, 1u);
                            if (gp2 < CAP) cand[gp2] = entry;
                        }
                    }
                }
            }
        }
    }
    __syncthreads();
    if (t == 0) {
        unsigned m = *scnt;
        if (m > SCAP) m = SCAP;
        *scnt = m;
        *sbase = atomicAdd(cnt, m);
    }
    if (t < 128) {   // cross-half merge + fire-and-forget global min
        float d0 = sbd[t], d1 = sbd[128 + t];
        int   i0 = sbk[t], i1 = sbk[128 + t];
        float bd; int bk;
        if (d1 < d0 || (d1 == d0 && i1 < i0)) { bd = d1; bk = i1; }
        else                                  { bd = d0; bk = i0; }
        unsigned long long p =
            ((unsigned long long)__float_as_uint(bd) << 32) | (unsigned)bk;
        atomicMin(&packed[m0 + t], p);
    }
    // wave-level dsum reduce (no LDS-barrier ladder)
#pragma unroll
    for (int off = 1; off < 64; off <<= 1)
        dsum += __shfl_xor(dsum, off, 64);
    if (lane == 0) swred[w] = dsum;
    __syncthreads();
    {
        unsigned m = *scnt, b0 = *sbase;
        for (unsigned u = t; u < m; u += 256)
            if (b0 + u < CAP) cand[b0 + u] = scand[u];
    }
    if (t == 0)
        atomicAdd(&accums[0], (swred[0] + swred[1]) + (swred[2] + swred[3]));
}

// ---------------------------------------------------------------------------
// Phase-2: re-filter candidates against FINAL row min, rescore survivors
// exactly from (hi+lo) pairs, lex atomicMin into packed2. One wave/entry.
// ---------------------------------------------------------------------------
__global__ __launch_bounds__(256) void k_rescore(const unsigned long long* __restrict__ cand,
                                                 const unsigned short* __restrict__ Ahi,
                                                 const unsigned short* __restrict__ Alo,
                                                 const unsigned short* __restrict__ Bhi,
                                                 const unsigned short* __restrict__ Blo,
                                                 const float* __restrict__ zsq,
                                                 const float* __restrict__ csq,
                                                 const float* __restrict__ zlosq,
                                                 const float* __restrict__ closq,
                                                 const unsigned long long* __restrict__ packed,
                                                 unsigned long long* __restrict__ packed2,
                                                 const float* __restrict__ accums) {
    unsigned total = *(const unsigned*)&accums[2];
    if (total > CAP) total = CAP;
    float M1 = sqrtf(accums[3]);
    float M2 = sqrtf(accums[4]);
    int lane = threadIdx.x & 63;
    unsigned wv = blockIdx.x * 4 + (threadIdx.x >> 6);
    unsigned nw = gridDim.x * 4;
    for (unsigned e = wv; e < total; e += nw) {
        unsigned long long ent = cand[e];
        float dhi = __uint_as_float((unsigned)(ent >> 32));
        unsigned nk = (unsigned)ent;
        int n = (nk >> 13) & 16383;
        int k = nk & 8191;
        float g = __uint_as_float((unsigned)(packed[n] >> 32));
        float a  = 2.1f * sqrtf(zlosq[n]);
        float bb = 2.1f * sqrtf(zsq[n]);
        float marg = g + 1e-3f + a * (M1 + sqrtf(csq[k])) + bb * (M2 + sqrtf(closq[k]));
        if (dhi > marg) continue;
        ushort4 zh = *((const ushort4*)(Ahi + (size_t)n * 256) + lane);
        ushort4 zl = *((const ushort4*)(Alo + (size_t)n * 256) + lane);
        ushort4 ch = *((const ushort4*)(Bhi + (size_t)k * 256) + lane);
        ushort4 cl = *((const ushort4*)(Blo + (size_t)k * 256) + lane);
        float s = (bf2f(zh.x) + bf2f(zl.x)) * (bf2f(ch.x) + bf2f(cl.x))
                + (bf2f(zh.y) + bf2f(zl.y)) * (bf2f(ch.y) + bf2f(cl.y))
                + (bf2f(zh.z) + bf2f(zl.z)) * (bf2f(ch.z) + bf2f(cl.z))
                + (bf2f(zh.w) + bf2f(zl.w)) * (bf2f(ch.w) + bf2f(cl.w));
#pragma unroll
        for (int off = 1; off < 64; off <<= 1)
            s += __shfl_xor(s, off, 64);
        if (lane == 0) {
            float dd = (zsq[n] + csq[k]) - 2.0f * s;
            unsigned long long p =
                ((unsigned long long)__float_as_uint(dd) << 32) | (unsigned)k;
            atomicMin(&packed2[n], p);
        }
    }
}

// ---------------------------------------------------------------------------
// Unpack argmin + histogram
// ---------------------------------------------------------------------------
__global__ void k_unpack(const unsigned long long* __restrict__ packed2,
                         int* __restrict__ idx, int* __restrict__ counts) {
    int n = blockIdx.x * 256 + threadIdx.x;
    unsigned long long p = packed2[n];
    int k = (int)(p & 0xffffffffull);
    idx[n] = k;
    atomicAdd(&counts[k], 1);
}

// ---------------------------------------------------------------------------
// z_q gather (channels-first) + loss partial sums
// ---------------------------------------------------------------------------
__global__ void k_zqloss(const float* __restrict__ z, const float* __restrict__ C_t,
                         const int* __restrict__ idx, float* __restrict__ out,
                         float* __restrict__ loss_sum) {
    __shared__ float red[256];
    int bid = blockIdx.x;
    int b = bid >> 8;
    int d = bid & 255;
    int t = threadIdx.x;
    const float* crow = C_t + (size_t)d * KCB;
    const int* ib = idx + b * THW;
    size_t base = ((size_t)(b * DIM + d)) * THW;
    float lsum = 0.f;
    for (int it = 0; it < 32; ++it) {
        int thw = it * 256 + t;
        int id = ib[thw];
        float v = crow[id];
        float zz = z[base + thw];
        out[base + thw] = v;
        float df = v - zz;
        lsum += df * df;
    }
    red[t] = lsum;
    __syncthreads();
    for (int s = 128; s > 0; s >>= 1) {
        if (t < s) red[t] += red[t + s];
        __syncthreads();
    }
    if (t == 0) atomicAdd(loss_sum, red[0]);
}

// ---------------------------------------------------------------------------
// Final scalars
// ---------------------------------------------------------------------------
__global__ void k_scalars(const int* __restrict__ counts,
                          const float* __restrict__ accums,
                          float* __restrict__ out_tail) {
    __shared__ float red[256];
    int t = threadIdx.x;
    float s = 0.f;
    for (int k = t; k < KCB; k += 256) {
        float e = (float)counts[k] * (1.0f / 16384.0f);
        s += e * logf(e + 1e-10f);
    }
    red[t] = s;
    __syncthreads();
    for (int st = 128; st > 0; st >>= 1) {
        if (t < st) red[t] += red[t + st];
        __syncthreads();
    }
    if (t == 0) {
        out_tail[0] = 1.25f * accums[1] / 4194304.0f;
        out_tail[1] = expf(-red[0]);
        out_tail[2] = accums[0] / (16384.0f * 8192.0f);
    }
}

// ---------------------------------------------------------------------------
extern "C" void kernel_launch(void* const* d_in, const int* in_sizes, int n_in,
                              void* d_out, int out_size, void* d_ws, size_t ws_size,
                              hipStream_t stream) {
    const float* z     = (const float*)d_in[0];   // [2][256][8192]
    const float* emb_w = (const float*)d_in[1];   // [8192][256]
    const float* w1    = (const float*)d_in[2];   // [256][256]
    const float* w2    = (const float*)d_in[3];   // [256][256]
    float* out = (float*)d_out;

    char* w = (char*)d_ws;
    unsigned short* Ahi = (unsigned short*)(w + 0);          //  8,388,608 B
    unsigned short* Alo = (unsigned short*)(w + 8388608);    //  8,388,608 B
    float* R1    = (float*)(w + 16777216);   // emb_t, aliased by C_t (8,388,608 B)
    float* H_t   = (float*)(w + 25165824);   //  8,388,608 B
    unsigned short* Bhi = (unsigned short*)(w + 33554432);   //  4,194,304 B
    unsigned short* Blo = (unsigned short*)(w + 37748736);   //  4,194,304 B
    float* w1t   = (float*)(w + 41943040);   //    262,144 B
    float* w2t   = (float*)(w + 42205184);   //    262,144 B
    float* zsq   = (float*)(w + 42467328);   //     65,536 B
    float* csq   = (float*)(w + 42532864);   //     32,768 B
    float* zlosq = (float*)(w + 42565632);   //     65,536 B
    float* closq = (float*)(w + 42631168);   //     32,768 B
    unsigned long long* packed  = (unsigned long long*)(w + 42663936); // 131,072 B
    unsigned long long* packed2 = (unsigned long long*)(w + 42795008); // 131,072 B
    int*   idx    = (int*)(w + 42926080);    //     65,536 B
    int*   counts = (int*)(w + 42991616);    //     32,768 B
    float* accums = (float*)(w + 43024384);  // [0]dsum [1]loss [2]cnt [3]csqmax [4]closqmax

    float* emb_t = R1;
    float* C_t   = R1;                        // alias: emb_t dead after gemm#1
    // candidate buffer lives in d_out: dead before k_zqloss writes z_q
    unsigned long long* cand = (unsigned long long*)d_out;   // 16,000,000 B

    hipMemsetAsync(counts, 0, 32768 + 32, stream);           // counts + accums
    hipMemsetAsync(packed, 0xFF, 262144, stream);            // packed + packed2

    // hi/lo split of z + norms
    k_buildA<<<NTOK / 64, 256, 0, stream>>>(z, Ahi, Alo, zsq, zlosq);

    // transposes for the MLP GEMMs
    {
        dim3 blk(32, 8);
        k_transpose<<<dim3(DIM / 32, KCB / 32), blk, 0, stream>>>(emb_w, emb_t, KCB, DIM);
        k_transpose<<<dim3(DIM / 32, DIM / 32), blk, 0, stream>>>(w1, w1t, DIM, DIM);
        k_transpose<<<dim3(DIM / 32, DIM / 32), blk, 0, stream>>>(w2, w2t, DIM, DIM);
    }
    // codebook MLP: H_t = gelu(w1 @ emb^T) ; C_t = w2 @ H^T
    k_gemm_tt<1><<<dim3(KCB / 128, DIM / 64), 512, 0, stream>>>(w1t, emb_t, H_t, DIM, KCB);
    k_gemm_tt<0><<<dim3(KCB / 128, DIM / 64), 512, 0, stream>>>(w2t, H_t, C_t, DIM, KCB);
    // hi/lo split of codebook + norms + maxima
    k_buildB<<<KCB / 64, 256, 0, stream>>>(C_t, Bhi, Blo, csq, closq, accums);

    // Phase-1: d_hi GEMM + row-min + fused candidate append + sum(d)
    k_dist_hi<<<dim3(NTOK / 128, KCB / 128), 256, 0, stream>>>(
        Ahi, Bhi, zsq, csq, zlosq, closq, packed, accums, cand);

    // Phase-2: exact rescore of survivors
    k_rescore<<<1024, 256, 0, stream>>>(cand, Ahi, Alo, Bhi, Blo, zsq, csq,
                                        zlosq, closq, packed, packed2, accums);

    k_unpack<<<NTOK / 256, 256, 0, stream>>>(packed2, idx, counts);
    k_zqloss<<<BATCH * DIM, 256, 0, stream>>>(z, C_t, idx, out, accums + 1);
    k_scalars<<<1, 256, 0, stream>>>(counts, accums, out + OUTQ);
}

// Round 8
// 564.044 us; speedup vs baseline: 3.8168x; 1.0802x over previous
//
#include <hip/hip_runtime.h>
#include <math.h>

// Problem constants (fixed by setup_inputs)
#define BATCH 2
#define DIM   256
#define THW   8192            // T*H*W = 8*32*32
#define NTOK  16384           // BATCH*THW
#define KCB   8192            // codebook size
#define OUTQ  4194304         // BATCH*DIM*THW
#define CAP   2000000         // candidate buffer entries (16 MB in d_out)
#define SCAP  3710            // per-block LDS candidate staging capacity

typedef short short8 __attribute__((ext_vector_type(8)));
typedef float f32x4 __attribute__((ext_vector_type(4)));

__device__ __forceinline__ unsigned short f2bf_rn(float v) {
    unsigned u = __float_as_uint(v);
    unsigned r = u + 0x7FFFu + ((u >> 16) & 1u);
    return (unsigned short)(r >> 16);
}
__device__ __forceinline__ float bf2f(unsigned short b) {
    return __uint_as_float((unsigned)b << 16);
}
__device__ __forceinline__ void gl2lds16(const unsigned short* g, unsigned short* l) {
    __builtin_amdgcn_global_load_lds(
        (const __attribute__((address_space(1))) void*)g,
        (__attribute__((address_space(3))) void*)l, 16, 0, 0);
}

// ---------------------------------------------------------------------------
// buildA: z -> Ahi/Alo [NTOK][256]; zsq, zlosq, sA=2.1*sqrt(zlosq),
// sB=2.1*sqrt(zsq); per-block per-dim partial sums of z -> partialZ[blk][256]
// ---------------------------------------------------------------------------
__global__ void k_buildA(const float* __restrict__ z,
                         unsigned short* __restrict__ Ahi,
                         unsigned short* __restrict__ Alo,
                         float* __restrict__ zsq, float* __restrict__ zlosq,
                         float* __restrict__ sA, float* __restrict__ sB,
                         float* __restrict__ partialZ) {
    __shared__ ushort2 tile[64][65];
    __shared__ float zacc[64];
    __shared__ float lacc[64];
    __shared__ float pz[256];
    int t = threadIdx.x;
    int n0 = blockIdx.x * 64;
    int b = n0 >> 13;
    int thw0 = n0 & 8191;
    if (t < 64) { zacc[t] = 0.f; lacc[t] = 0.f; }
    pz[t] = 0.f;
    __syncthreads();
    int nn_r = t & 63, dg = t >> 6;
    float a1 = 0.f, a2 = 0.f;
    for (int dc = 0; dc < 256; dc += 64) {
        for (int r = 0; r < 16; ++r) {
            int dd = r * 4 + dg;
            float v = z[((size_t)(b * 256 + dc + dd)) * 8192 + thw0 + nn_r];
            unsigned short hb = f2bf_rn(v);
            float hf = bf2f(hb);
            unsigned short lb = f2bf_rn(v - hf);
            float lf = bf2f(lb);
            tile[dd][nn_r] = make_ushort2(hb, lb);
            a1 += v * v;
            a2 += lf * lf;
        }
        __syncthreads();
        int kk = t & 63, ng = t >> 6;
        float dimsum = 0.f;
        for (int i2 = 0; i2 < 16; ++i2) {
            int nn = ng + i2 * 4;
            ushort2 hl = tile[kk][nn];
            size_t base = (size_t)(n0 + nn) * 256;
            Ahi[base + dc + kk] = hl.x;
            Alo[base + dc + kk] = hl.y;
            dimsum += bf2f(hl.x) + bf2f(hl.y);
        }
        atomicAdd(&pz[dc + kk], dimsum);
        __syncthreads();
    }
    atomicAdd(&zacc[nn_r], a1);
    atomicAdd(&lacc[nn_r], a2);
    __syncthreads();
    if (t < 64) {
        zsq[n0 + t] = zacc[t];
        zlosq[n0 + t] = lacc[t];
        sA[n0 + t] = 2.1f * sqrtf(lacc[t]);
        sB[n0 + t] = 2.1f * sqrtf(zacc[t]);
    }
    partialZ[blockIdx.x * 256 + t] = pz[t];
}

// ---------------------------------------------------------------------------
// splitW: w (row-major [256][256]) -> Ws [256][768] = [whi|whi|wlo]
// grid 512: bid>>8 selects matrix, bid&255 = row; thread = column e
// ---------------------------------------------------------------------------
__global__ void k_splitW(const float* __restrict__ w1, const float* __restrict__ w2,
                         unsigned short* __restrict__ W1s, unsigned short* __restrict__ W2s) {
    int bid = blockIdx.x;
    int row = bid & 255;
    const float* src = (bid >> 8) ? w2 : w1;
    unsigned short* dst = ((bid >> 8) ? W2s : W1s) + (size_t)row * 768;
    int t = threadIdx.x;
    float v = src[row * 256 + t];
    unsigned short hb = f2bf_rn(v);
    unsigned short lb = f2bf_rn(v - bf2f(hb));
    dst[t] = hb;
    dst[256 + t] = hb;
    dst[512 + t] = lb;
}

// ---------------------------------------------------------------------------
// buildE: emb [8192][256] -> E' [8192][768] = [ehi|elo|ehi]
// ---------------------------------------------------------------------------
__global__ void k_buildE(const float* __restrict__ emb, unsigned short* __restrict__ E) {
    int t = threadIdx.x;
    int row = blockIdx.x * 4 + (t >> 6);
    int e4 = (t & 63) * 4;
    float4 v = *(const float4*)&emb[(size_t)row * 256 + e4];
    ushort4 hi, lo;
    hi.x = f2bf_rn(v.x); lo.x = f2bf_rn(v.x - bf2f(hi.x));
    hi.y = f2bf_rn(v.y); lo.y = f2bf_rn(v.y - bf2f(hi.y));
    hi.z = f2bf_rn(v.z); lo.z = f2bf_rn(v.z - bf2f(hi.z));
    hi.w = f2bf_rn(v.w); lo.w = f2bf_rn(v.w - bf2f(hi.w));
    size_t base = (size_t)row * 768;
    *(ushort4*)&E[base + e4] = hi;
    *(ushort4*)&E[base + 256 + e4] = lo;
    *(ushort4*)&E[base + 512 + e4] = hi;
}

// ---------------------------------------------------------------------------
// MLP GEMM on split-bf16 MFMA: A [M][768] ([whi|whi|wlo]) x B [8192][768]
// ([xhi|xlo|xhi]); r3 2-barrier K-loop (12 kc), XOR chunk swizzle.
// GELU=1: out Hs[k][768] = split(gelu(h)) ([hhi|hlo|hhi], scatter stores)
// GELU=0: out C_t[d][8192] = h (coalesced)
// ---------------------------------------------------------------------------
template <int GELU>
__global__ __launch_bounds__(256) void k_mlp(const unsigned short* __restrict__ A,
                                             const unsigned short* __restrict__ B,
                                             unsigned short* __restrict__ Hs,
                                             float* __restrict__ C_t) {
    __shared__ __align__(16) char smem[32768];
    unsigned short* Asm = (unsigned short*)smem;
    unsigned short* Bsm = (unsigned short*)(smem + 16384);

    int t = threadIdx.x;
    int lane = t & 63;
    int w = t >> 6;
    int wm = w >> 1, wn = w & 1;
    int m0 = blockIdx.y * 128;
    int n0 = blockIdx.x * 128;

    int rA = w * 8 + (lane >> 3);
    int ch_l = lane & 7;
    int ch_g = ch_l ^ (lane >> 3);
    const unsigned short* gA = A + (size_t)(m0 + rA) * 768 + ch_g * 8;
    const unsigned short* gB = B + (size_t)(n0 + rA) * 768 + ch_g * 8;
    unsigned short* lA = &Asm[rA * 64 + ch_l * 8];
    unsigned short* lB = &Bsm[rA * 64 + ch_l * 8];

    f32x4 acc[4][4];
#pragma unroll
    for (int i = 0; i < 4; ++i)
#pragma unroll
        for (int j = 0; j < 4; ++j)
            acc[i][j] = f32x4{0.f, 0.f, 0.f, 0.f};

#pragma unroll
    for (int i = 0; i < 4; ++i) {
        gl2lds16(gA + (size_t)(32 * i) * 768, lA + 32 * i * 64);
        gl2lds16(gB + (size_t)(32 * i) * 768, lB + 32 * i * 64);
    }
    __syncthreads();

    int l15 = lane & 15;
    int quad = lane >> 4;
    int sw = l15 & 7;
    for (int kc = 0; kc < 12; ++kc) {
#pragma unroll
        for (int kk = 0; kk < 2; ++kk) {
            short8 a[4], b[4];
#pragma unroll
            for (int i = 0; i < 4; ++i)
                a[i] = *(const short8*)&Asm[(wm * 64 + i * 16 + l15) * 64 +
                                            (((kk * 4 + quad) ^ sw) * 8)];
#pragma unroll
            for (int j = 0; j < 4; ++j)
                b[j] = *(const short8*)&Bsm[(wn * 64 + j * 16 + l15) * 64 +
                                            (((kk * 4 + quad) ^ sw) * 8)];
#pragma unroll
            for (int i = 0; i < 4; ++i)
#pragma unroll
                for (int j = 0; j < 4; ++j)
                    acc[i][j] = __builtin_amdgcn_mfma_f32_16x16x32_bf16(a[i], b[j], acc[i][j], 0, 0, 0);
        }
        __syncthreads();
        if (kc < 11) {
            int ko = (kc + 1) * 64;
#pragma unroll
            for (int i = 0; i < 4; ++i) {
                gl2lds16(gA + (size_t)(32 * i) * 768 + ko, lA + 32 * i * 64);
                gl2lds16(gB + (size_t)(32 * i) * 768 + ko, lB + 32 * i * 64);
            }
            __syncthreads();
        }
    }

    // epilogue: C/D layout col=lane&15, row=quad*4+reg
#pragma unroll
    for (int i = 0; i < 4; ++i) {
#pragma unroll
        for (int reg = 0; reg < 4; ++reg) {
            int drow = m0 + wm * 64 + i * 16 + quad * 4 + reg;
#pragma unroll
            for (int j = 0; j < 4; ++j) {
                int kcol = n0 + wn * 64 + j * 16 + l15;
                float h = acc[i][j][reg];
                if (GELU) {
                    float g = 0.5f * h * (1.f + erff(h * 0.70710678118654752f));
                    unsigned short hb = f2bf_rn(g);
                    unsigned short lb = f2bf_rn(g - bf2f(hb));
                    size_t base = (size_t)kcol * 768;
                    Hs[base + drow] = hb;
                    Hs[base + 256 + drow] = lb;
                    Hs[base + 512 + drow] = hb;
                } else {
                    C_t[(size_t)drow * 8192 + kcol] = h;
                }
            }
        }
    }
}

// ---------------------------------------------------------------------------
// buildB: C_t [256][8192] -> Bhi/Blo [KCB][256]; csq, closq, sC=sqrt(csq),
// sCl=sqrt(closq); per-128-tile maxima of sC/sCl; global csq/closq maxima;
// per-dim partial sums -> partialC[blk][256]
// ---------------------------------------------------------------------------
__global__ void k_buildB(const float* __restrict__ C_t,
                         unsigned short* __restrict__ Bhi,
                         unsigned short* __restrict__ Blo,
                         float* __restrict__ csq, float* __restrict__ closq,
                         float* __restrict__ sC, float* __restrict__ sCl,
                         unsigned* __restrict__ tileMaxC, unsigned* __restrict__ tileMaxCl,
                         float* __restrict__ accums, float* __restrict__ partialC) {
    __shared__ ushort2 tile[64][65];
    __shared__ float kacc[64];
    __shared__ float lacc[64];
    __shared__ float pc[256];
    int t = threadIdx.x;
    int k0 = blockIdx.x * 64;
    if (t < 64) { kacc[t] = 0.f; lacc[t] = 0.f; }
    pc[t] = 0.f;
    __syncthreads();
    int nn_r = t & 63, dg = t >> 6;
    float a1 = 0.f, a2 = 0.f;
    for (int dc = 0; dc < 256; dc += 64) {
        for (int r = 0; r < 16; ++r) {
            int dd = r * 4 + dg;
            float v = C_t[(size_t)(dc + dd) * KCB + k0 + nn_r];
            unsigned short hb = f2bf_rn(v);
            float hf = bf2f(hb);
            unsigned short lb = f2bf_rn(v - hf);
            float lf = bf2f(lb);
            tile[dd][nn_r] = make_ushort2(hb, lb);
            a1 += v * v;
            a2 += lf * lf;
        }
        __syncthreads();
        int kk = t & 63, ng = t >> 6;
        float dimsum = 0.f;
        for (int i2 = 0; i2 < 16; ++i2) {
            int nn = ng + i2 * 4;
            ushort2 hl = tile[kk][nn];
            size_t base = (size_t)(k0 + nn) * 256;
            Bhi[base + dc + kk] = hl.x;
            Blo[base + dc + kk] = hl.y;
            dimsum += bf2f(hl.x) + bf2f(hl.y);
        }
        atomicAdd(&pc[dc + kk], dimsum);
        __syncthreads();
    }
    atomicAdd(&kacc[nn_r], a1);
    atomicAdd(&lacc[nn_r], a2);
    __syncthreads();
    if (t < 64) {
        float c2 = kacc[t], l2 = lacc[t];
        float sc = sqrtf(c2), sl = sqrtf(l2);
        csq[k0 + t] = c2;
        closq[k0 + t] = l2;
        sC[k0 + t] = sc;
        sCl[k0 + t] = sl;
        int tl = blockIdx.x >> 1;
        atomicMax(&tileMaxC[tl], __float_as_uint(sc));
        atomicMax(&tileMaxCl[tl], __float_as_uint(sl));
        atomicMax((unsigned*)&accums[3], __float_as_uint(c2));
        atomicMax((unsigned*)&accums[4], __float_as_uint(l2));
    }
    partialC[blockIdx.x * 256 + t] = pc[t];
}

// ---------------------------------------------------------------------------
// Phase-1: d_hi GEMM (K=256) + slim epilogue:
//  pass1: transform acc->d in place, per-row shuffle min
//  t<128: merge, fire-and-forget atomicMin, thr[row] (row-constant margin
//         using per-tile maxima — winner retention proof as r5)
//  pass2: 1-compare-per-element filter, LDS-staged appends
// ---------------------------------------------------------------------------
__global__ __launch_bounds__(256) void k_dist_hi(const unsigned short* __restrict__ A,
                                                 const unsigned short* __restrict__ B,
                                                 const float* __restrict__ zsq,
                                                 const float* __restrict__ csq,
                                                 const float* __restrict__ sA,
                                                 const float* __restrict__ sB,
                                                 const unsigned* __restrict__ tileMaxC,
                                                 const unsigned* __restrict__ tileMaxCl,
                                                 unsigned long long* __restrict__ packed,
                                                 float* __restrict__ accums,
                                                 unsigned long long* __restrict__ cand) {
    __shared__ __align__(16) char smem[32768];
    unsigned short* Asm = (unsigned short*)smem;           // [128][64]
    unsigned short* Bsm = (unsigned short*)(smem + 16384); // [128][64]
    float* sbd     = (float*)smem;                   // [2][128]
    int*   sbk     = (int*)(smem + 1024);            // [2][128]
    float* gprev_s = (float*)(smem + 2048);          // [128]
    float* thr     = (float*)(smem + 2560);          // [128]
    unsigned* scnt  = (unsigned*)(smem + 3072);
    unsigned* sbase = (unsigned*)(smem + 3076);
    unsigned long long* scand = (unsigned long long*)(smem + 3088); // [SCAP]

    int t = threadIdx.x;
    int lane = t & 63;
    int w = t >> 6;
    int wm = w >> 1, wn = w & 1;
    int m0 = blockIdx.x * 128;
    int n0 = blockIdx.y * 128;

    int rA = w * 8 + (lane >> 3);
    int ch_l = lane & 7;
    int ch_g = ch_l ^ (lane >> 3);
    const unsigned short* gA = A + (size_t)(m0 + rA) * 256 + ch_g * 8;
    const unsigned short* gB = B + (size_t)(n0 + rA) * 256 + ch_g * 8;
    unsigned short* lA = &Asm[rA * 64 + ch_l * 8];
    unsigned short* lB = &Bsm[rA * 64 + ch_l * 8];

    int l15 = lane & 15;
    int quad = lane >> 4;
    int sw = l15 & 7;

    // hoisted epilogue constants
    float M1 = sqrtf(accums[3]);
    float M2 = sqrtf(accums[4]);
    float msC  = __uint_as_float(tileMaxC[blockIdx.y]);
    float msCl = __uint_as_float(tileMaxCl[blockIdx.y]);
    float cv[4];
    int cols[4];
#pragma unroll
    for (int j = 0; j < 4; ++j) {
        int cloc = wn * 64 + j * 16 + l15;
        cols[j] = n0 + cloc;
        cv[j] = csq[cols[j]];
    }

    f32x4 acc[4][4];
#pragma unroll
    for (int i = 0; i < 4; ++i)
#pragma unroll
        for (int j = 0; j < 4; ++j)
            acc[i][j] = f32x4{0.f, 0.f, 0.f, 0.f};

#pragma unroll
    for (int i = 0; i < 4; ++i) {
        gl2lds16(gA + (size_t)(32 * i) * 256, lA + 32 * i * 64);
        gl2lds16(gB + (size_t)(32 * i) * 256, lB + 32 * i * 64);
    }
    __syncthreads();

    for (int kc = 0; kc < 4; ++kc) {
#pragma unroll
        for (int kk = 0; kk < 2; ++kk) {
            short8 a[4], b[4];
#pragma unroll
            for (int i = 0; i < 4; ++i)
                a[i] = *(const short8*)&Asm[(wm * 64 + i * 16 + l15) * 64 +
                                            (((kk * 4 + quad) ^ sw) * 8)];
#pragma unroll
            for (int j = 0; j < 4; ++j)
                b[j] = *(const short8*)&Bsm[(wn * 64 + j * 16 + l15) * 64 +
                                            (((kk * 4 + quad) ^ sw) * 8)];
#pragma unroll
            for (int i = 0; i < 4; ++i)
#pragma unroll
                for (int j = 0; j < 4; ++j)
                    acc[i][j] = __builtin_amdgcn_mfma_f32_16x16x32_bf16(a[i], b[j], acc[i][j], 0, 0, 0);
        }
        __syncthreads();
        if (kc < 3) {
            int ko = (kc + 1) * 64;
#pragma unroll
            for (int i = 0; i < 4; ++i) {
                gl2lds16(gA + (size_t)(32 * i) * 256 + ko, lA + 32 * i * 64);
                gl2lds16(gB + (size_t)(32 * i) * 256 + ko, lB + 32 * i * 64);
            }
            __syncthreads();
        }
    }

    // ---- pass 1: transform in place + per-row min reduce
    if (t == 0) *scnt = 0;
    if (t < 128) {
        const unsigned* hp = (const unsigned*)&packed[m0 + t];
        gprev_s[t] = __uint_as_float(__atomic_load_n(hp + 1, __ATOMIC_RELAXED));
    }
#pragma unroll
    for (int i = 0; i < 4; ++i) {
#pragma unroll
        for (int reg = 0; reg < 4; ++reg) {
            int rloc = wm * 64 + i * 16 + quad * 4 + reg;
            float zs = zsq[m0 + rloc];
            float bd = 3.4e38f;
            int   bk = 0x7fffffff;
#pragma unroll
            for (int j = 0; j < 4; ++j) {
                float dd = (zs + cv[j]) - 2.0f * acc[i][j][reg];
                acc[i][j][reg] = dd;
                if (dd < bd || (dd == bd && cols[j] < bk)) { bd = dd; bk = cols[j]; }
            }
#pragma unroll
            for (int off = 1; off < 16; off <<= 1) {
                float od = __shfl_xor(bd, off, 64);
                int   ok = __shfl_xor(bk, off, 64);
                if (od < bd || (od == bd && ok < bk)) { bd = od; bk = ok; }
            }
            if (l15 == 0) { sbd[wn * 128 + rloc] = bd; sbk[wn * 128 + rloc] = bk; }
        }
    }
    __syncthreads();
    // ---- t<128: merge halves, global min (fire-and-forget), row threshold
    if (t < 128) {
        float d0 = sbd[t], d1 = sbd[128 + t];
        int   i0 = sbk[t], i1 = sbk[128 + t];
        float bd; int bk;
        if (d1 < d0 || (d1 == d0 && i1 < i0)) { bd = d1; bk = i1; }
        else                                  { bd = d0; bk = i0; }
        unsigned long long p =
            ((unsigned long long)__float_as_uint(bd) << 32) | (unsigned)bk;
        atomicMin(&packed[m0 + t], p);
        float g = fminf(bd, gprev_s[t]);
        thr[t] = g + 1e-3f + sA[m0 + t] * (M1 + msC) + sB[m0 + t] * (M2 + msCl);
    }
    __syncthreads();
    // ---- pass 2: 1-compare filter + staged appends
    unsigned* cnt = (unsigned*)&accums[2];
#pragma unroll
    for (int i = 0; i < 4; ++i) {
#pragma unroll
        for (int reg = 0; reg < 4; ++reg) {
            int rloc = wm * 64 + i * 16 + quad * 4 + reg;
            float tr = thr[rloc];
            bool p0 = acc[i][0][reg] <= tr;
            bool p1 = acc[i][1][reg] <= tr;
            bool p2 = acc[i][2][reg] <= tr;
            bool p3 = acc[i][3][reg] <= tr;
            if (__ballot(p0 | p1 | p2 | p3)) {
                unsigned rbits = (unsigned)((m0 + rloc) << 13);
#pragma unroll
                for (int j = 0; j < 4; ++j) {
                    bool p = (j == 0) ? p0 : (j == 1) ? p1 : (j == 2) ? p2 : p3;
                    if (p) {
                        unsigned long long entry =
                            ((unsigned long long)__float_as_uint(acc[i][j][reg]) << 32) |
                            (rbits | (unsigned)cols[j]);
                        unsigned pos = atomicAdd(scnt, 1u);
                        if (pos < SCAP) scand[pos] = entry;
                        else {
                            unsigned gp2 = atomicAdd(cnt, 1u);
                            if (gp2 < CAP) cand[gp2] = entry;
                        }
                    }
                }
            }
        }
    }
    __syncthreads();
    if (t == 0) {
        unsigned m = *scnt;
        if (m > SCAP) m = SCAP;
        *scnt = m;
        *sbase = atomicAdd(cnt, m);
    }
    __syncthreads();
    {
        unsigned m = *scnt, b0 = *sbase;
        for (unsigned u = t; u < m; u += 256)
            if (b0 + u < CAP) cand[b0 + u] = scand[u];
    }
}

// ---------------------------------------------------------------------------
// Phase-2: re-filter vs final row min, exact rescore, lex atomicMin
// ---------------------------------------------------------------------------
__global__ __launch_bounds__(256) void k_rescore(const unsigned long long* __restrict__ cand,
                                                 const unsigned short* __restrict__ Ahi,
                                                 const unsigned short* __restrict__ Alo,
                                                 const unsigned short* __restrict__ Bhi,
                                                 const unsigned short* __restrict__ Blo,
                                                 const float* __restrict__ zsq,
                                                 const float* __restrict__ csq,
                                                 const float* __restrict__ sA,
                                                 const float* __restrict__ sB,
                                                 const float* __restrict__ sC,
                                                 const float* __restrict__ sCl,
                                                 const unsigned long long* __restrict__ packed,
                                                 unsigned long long* __restrict__ packed2,
                                                 const float* __restrict__ accums) {
    unsigned total = *(const unsigned*)&accums[2];
    if (total > CAP) total = CAP;
    float M1 = sqrtf(accums[3]);
    float M2 = sqrtf(accums[4]);
    int lane = threadIdx.x & 63;
    unsigned wv = blockIdx.x * 4 + (threadIdx.x >> 6);
    unsigned nw = gridDim.x * 4;
    for (unsigned e = wv; e < total; e += nw) {
        unsigned long long ent = cand[e];
        float dhi = __uint_as_float((unsigned)(ent >> 32));
        unsigned nk = (unsigned)ent;
        int n = (nk >> 13) & 16383;
        int k = nk & 8191;
        float g = __uint_as_float((unsigned)(packed[n] >> 32));
        float marg = g + 1e-3f + sA[n] * (M1 + sC[k]) + sB[n] * (M2 + sCl[k]);
        if (dhi > marg) continue;
        ushort4 zh = *((const ushort4*)(Ahi + (size_t)n * 256) + lane);
        ushort4 zl = *((const ushort4*)(Alo + (size_t)n * 256) + lane);
        ushort4 ch = *((const ushort4*)(Bhi + (size_t)k * 256) + lane);
        ushort4 cl = *((const ushort4*)(Blo + (size_t)k * 256) + lane);
        float s = (bf2f(zh.x) + bf2f(zl.x)) * (bf2f(ch.x) + bf2f(cl.x))
                + (bf2f(zh.y) + bf2f(zl.y)) * (bf2f(ch.y) + bf2f(cl.y))
                + (bf2f(zh.z) + bf2f(zl.z)) * (bf2f(ch.z) + bf2f(cl.z))
                + (bf2f(zh.w) + bf2f(zl.w)) * (bf2f(ch.w) + bf2f(cl.w));
#pragma unroll
        for (int off = 1; off < 64; off <<= 1)
            s += __shfl_xor(s, off, 64);
        if (lane == 0) {
            float dd = (zsq[n] + csq[k]) - 2.0f * s;
            unsigned long long p =
                ((unsigned long long)__float_as_uint(dd) << 32) | (unsigned)k;
            atomicMin(&packed2[n], p);
        }
    }
}

__global__ void k_unpack(const unsigned long long* __restrict__ packed2,
                         int* __restrict__ idx, int* __restrict__ counts) {
    int n = blockIdx.x * 256 + threadIdx.x;
    unsigned long long p = packed2[n];
    int k = (int)(p & 0xffffffffull);
    idx[n] = k;
    atomicAdd(&counts[k], 1);
}

__global__ void k_zqloss(const float* __restrict__ z, const float* __restrict__ C_t,
                         const int* __restrict__ idx, float* __restrict__ out,
                         float* __restrict__ loss_sum) {
    __shared__ float red[256];
    int bid = blockIdx.x;
    int b = bid >> 8;
    int d = bid & 255;
    int t = threadIdx.x;
    const float* crow = C_t + (size_t)d * KCB;
    const int* ib = idx + b * THW;
    size_t base = ((size_t)(b * DIM + d)) * THW;
    float lsum = 0.f;
    for (int it = 0; it < 32; ++it) {
        int thw = it * 256 + t;
        int id = ib[thw];
        float v = crow[id];
        float zz = z[base + thw];
        out[base + thw] = v;
        float df = v - zz;
        lsum += df * df;
    }
    red[t] = lsum;
    __syncthreads();
    for (int s = 128; s > 0; s >>= 1) {
        if (t < s) red[t] += red[t + s];
        __syncthreads();
    }
    if (t == 0) atomicAdd(loss_sum, red[0]);
}

// ---------------------------------------------------------------------------
// Final scalars: loss, perplexity, closed-form mean_distance
//   sum(d) = K*sum(zsq) + N*sum(csq) - 2*dot(sum_n z, sum_k c)
// ---------------------------------------------------------------------------
__global__ void k_scalars(const int* __restrict__ counts,
                          const float* __restrict__ accums,
                          const float* __restrict__ zsq, const float* __restrict__ csq,
                          const float* __restrict__ partialZ,
                          const float* __restrict__ partialC,
                          float* __restrict__ out_tail) {
    __shared__ double redd[256];
    __shared__ float redf[256];
    int t = threadIdx.x;
    double szsq = 0.0, scsq = 0.0;
    for (int n = t; n < NTOK; n += 256) szsq += (double)zsq[n];
    for (int k = t; k < KCB; k += 256) scsq += (double)csq[k];
    float SZ = 0.f, SC = 0.f;
    for (int b2 = 0; b2 < 256; ++b2) SZ += partialZ[b2 * 256 + t];
    for (int b2 = 0; b2 < 128; ++b2) SC += partialC[b2 * 256 + t];
    double total = 8192.0 * szsq + 16384.0 * scsq - 2.0 * (double)SZ * (double)SC;
    redd[t] = total;
    float s = 0.f;
    for (int k = t; k < KCB; k += 256) {
        float e = (float)counts[k] * (1.0f / 16384.0f);
        s += e * logf(e + 1e-10f);
    }
    redf[t] = s;
    __syncthreads();
    for (int st = 128; st > 0; st >>= 1) {
        if (t < st) { redd[t] += redd[t + st]; redf[t] += redf[t + st]; }
        __syncthreads();
    }
    if (t == 0) {
        out_tail[0] = 1.25f * accums[1] / 4194304.0f;
        out_tail[1] = expf(-redf[0]);
        out_tail[2] = (float)(redd[0] / (16384.0 * 8192.0));
    }
}

// ---------------------------------------------------------------------------
extern "C" void kernel_launch(void* const* d_in, const int* in_sizes, int n_in,
                              void* d_out, int out_size, void* d_ws, size_t ws_size,
                              hipStream_t stream) {
    const float* z     = (const float*)d_in[0];   // [2][256][8192]
    const float* emb_w = (const float*)d_in[1];   // [8192][256]
    const float* w1    = (const float*)d_in[2];   // [256][256]
    const float* w2    = (const float*)d_in[3];   // [256][256]
    float* out = (float*)d_out;

    char* w = (char*)d_ws;
    unsigned short* Ahi = (unsigned short*)(w + 0);          //  8,388,608
    unsigned short* Alo = (unsigned short*)(w + 8388608);    //  8,388,608
    unsigned short* Ebf = (unsigned short*)(w + 16777216);   // 12,582,912 (E'; C_t aliases after mlp1)
    unsigned short* Bhi = (unsigned short*)(w + 29360128);   //  4,194,304
    unsigned short* Blo = (unsigned short*)(w + 33554432);   //  4,194,304
    unsigned short* W1s = (unsigned short*)(w + 37748736);   //    393,216
    unsigned short* W2s = (unsigned short*)(w + 38141952);   //    393,216
    float* zsq   = (float*)(w + 38535168);   // 65,536
    float* zlosq = (float*)(w + 38600704);   // 65,536 (unused downstream but kept)
    float* sA    = (float*)(w + 38666240);   // 65,536
    float* sB    = (float*)(w + 38731776);   // 65,536
    float* csq   = (float*)(w + 38797312);   // 32,768
    float* closq = (float*)(w + 38830080);   // 32,768
    float* sC    = (float*)(w + 38862848);   // 32,768
    float* sCl   = (float*)(w + 38895616);   // 32,768
    unsigned long long* packed  = (unsigned long long*)(w + 38928384); // 131,072
    unsigned long long* packed2 = (unsigned long long*)(w + 39059456); // 131,072
    int*   idx    = (int*)(w + 39190528);    // 65,536
    int*   counts = (int*)(w + 39256064);    // 32,768
    float* partialZ = (float*)(w + 39288832); // 262,144
    float* partialC = (float*)(w + 39550976); // 131,072
    unsigned* tileMaxC  = (unsigned*)(w + 39682048); // 256
    unsigned* tileMaxCl = (unsigned*)(w + 39682304); // 256
    float* accums = (float*)(w + 39682560);  // [1]loss [2]cnt [3]csqmax [4]closqmax

    float* C_t = (float*)Ebf;                        // alias: E' dead after mlp1
    unsigned short* Hs = (unsigned short*)d_out;     // Hs then cand share d_out
    unsigned long long* cand = (unsigned long long*)d_out;

    hipMemsetAsync(counts, 0, 32768, stream);
    hipMemsetAsync(tileMaxC, 0, 1024, stream);       // tileMax* + accums
    hipMemsetAsync(packed, 0xFF, 262144, stream);    // packed + packed2

    k_buildA<<<NTOK / 64, 256, 0, stream>>>(z, Ahi, Alo, zsq, zlosq, sA, sB, partialZ);
    k_splitW<<<512, 256, 0, stream>>>(w1, w2, W1s, W2s);
    k_buildE<<<KCB / 4, 256, 0, stream>>>(emb_w, Ebf);

    // MLP: Hs = split(gelu(w1 x emb^T)) ; C_t = w2 x H^T (split-bf16 MFMA)
    k_mlp<1><<<dim3(KCB / 128, 2), 256, 0, stream>>>(W1s, Ebf, Hs, nullptr);
    k_mlp<0><<<dim3(KCB / 128, 2), 256, 0, stream>>>(W2s, Hs, nullptr, C_t);

    k_buildB<<<KCB / 64, 256, 0, stream>>>(C_t, Bhi, Blo, csq, closq, sC, sCl,
                                           tileMaxC, tileMaxCl, accums, partialC);

    k_dist_hi<<<dim3(NTOK / 128, KCB / 128), 256, 0, stream>>>(
        Ahi, Bhi, zsq, csq, sA, sB, tileMaxC, tileMaxCl, packed, accums, cand);

    k_rescore<<<1024, 256, 0, stream>>>(cand, Ahi, Alo, Bhi, Blo, zsq, csq,
                                        sA, sB, sC, sCl, packed, packed2, accums);

    k_unpack<<<NTOK / 256, 256, 0, stream>>>(packed2, idx, counts);
    k_zqloss<<<BATCH * DIM, 256, 0, stream>>>(z, C_t, idx, out, accums + 1);
    k_scalars<<<1, 256, 0, stream>>>(counts, accums, zsq, csq, partialZ, partialC, out + OUTQ);
}

// Round 9
// 450.815 us; speedup vs baseline: 4.7755x; 1.2512x over previous
//
#include <hip/hip_runtime.h>
#include <math.h>

// Problem constants (fixed by setup_inputs)
#define BATCH 2
#define DIM   256
#define THW   8192            // T*H*W = 8*32*32
#define NTOK  16384           // BATCH*THW
#define KCB   8192            // codebook size
#define OUTQ  4194304         // BATCH*DIM*THW
#define CAP   2000000         // candidate buffer entries (16 MB in d_out)
#define SCAP  5600            // per-block LDS candidate staging capacity

typedef short short8 __attribute__((ext_vector_type(8)));
typedef float f32x4 __attribute__((ext_vector_type(4)));

__device__ __forceinline__ unsigned short f2bf_rn(float v) {
    unsigned u = __float_as_uint(v);
    unsigned r = u + 0x7FFFu + ((u >> 16) & 1u);
    return (unsigned short)(r >> 16);
}
__device__ __forceinline__ float bf2f(unsigned short b) {
    return __uint_as_float((unsigned)b << 16);
}
__device__ __forceinline__ void gl2lds16(const unsigned short* g, unsigned short* l) {
    __builtin_amdgcn_global_load_lds(
        (const __attribute__((address_space(1))) void*)g,
        (__attribute__((address_space(3))) void*)l, 16, 0, 0);
}

// ---------------------------------------------------------------------------
// buildA: z -> Ahi/Alo [NTOK][256]; zsq, sA=2.1*sqrt(zlosq), sB=2.1*sqrt(zsq);
// per-block per-dim partial sums of z -> partialZ[blk][256]
// ---------------------------------------------------------------------------
__global__ void k_buildA(const float* __restrict__ z,
                         unsigned short* __restrict__ Ahi,
                         unsigned short* __restrict__ Alo,
                         float* __restrict__ zsq,
                         float* __restrict__ sA, float* __restrict__ sB,
                         float* __restrict__ partialZ) {
    __shared__ ushort2 tile[64][65];
    __shared__ float zacc[64];
    __shared__ float lacc[64];
    __shared__ float pz[256];
    int t = threadIdx.x;
    int n0 = blockIdx.x * 64;
    int b = n0 >> 13;
    int thw0 = n0 & 8191;
    if (t < 64) { zacc[t] = 0.f; lacc[t] = 0.f; }
    pz[t] = 0.f;
    __syncthreads();
    int nn_r = t & 63, dg = t >> 6;
    float a1 = 0.f, a2 = 0.f;
    for (int dc = 0; dc < 256; dc += 64) {
        for (int r = 0; r < 16; ++r) {
            int dd = r * 4 + dg;
            float v = z[((size_t)(b * 256 + dc + dd)) * 8192 + thw0 + nn_r];
            unsigned short hb = f2bf_rn(v);
            float hf = bf2f(hb);
            unsigned short lb = f2bf_rn(v - hf);
            float lf = bf2f(lb);
            tile[dd][nn_r] = make_ushort2(hb, lb);
            a1 += v * v;
            a2 += lf * lf;
        }
        __syncthreads();
        int kk = t & 63, ng = t >> 6;
        float dimsum = 0.f;
        for (int i2 = 0; i2 < 16; ++i2) {
            int nn = ng + i2 * 4;
            ushort2 hl = tile[kk][nn];
            size_t base = (size_t)(n0 + nn) * 256;
            Ahi[base + dc + kk] = hl.x;
            Alo[base + dc + kk] = hl.y;
            dimsum += bf2f(hl.x) + bf2f(hl.y);
        }
        atomicAdd(&pz[dc + kk], dimsum);
        __syncthreads();
    }
    atomicAdd(&zacc[nn_r], a1);
    atomicAdd(&lacc[nn_r], a2);
    __syncthreads();
    if (t < 64) {
        zsq[n0 + t] = zacc[t];
        sA[n0 + t] = 2.1f * sqrtf(lacc[t]);
        sB[n0 + t] = 2.1f * sqrtf(zacc[t]);
    }
    partialZ[blockIdx.x * 256 + t] = pz[t];
}

// ---------------------------------------------------------------------------
// splitW: w (row-major [256][256]) -> Ws [256][768] = [whi|whi|wlo]
// ---------------------------------------------------------------------------
__global__ void k_splitW(const float* __restrict__ w1, const float* __restrict__ w2,
                         unsigned short* __restrict__ W1s, unsigned short* __restrict__ W2s) {
    int bid = blockIdx.x;
    int row = bid & 255;
    const float* src = (bid >> 8) ? w2 : w1;
    unsigned short* dst = ((bid >> 8) ? W2s : W1s) + (size_t)row * 768;
    int t = threadIdx.x;
    float v = src[row * 256 + t];
    unsigned short hb = f2bf_rn(v);
    unsigned short lb = f2bf_rn(v - bf2f(hb));
    dst[t] = hb;
    dst[256 + t] = hb;
    dst[512 + t] = lb;
}

// ---------------------------------------------------------------------------
// buildE: emb [8192][256] -> E' [8192][768] = [ehi|elo|ehi]
// ---------------------------------------------------------------------------
__global__ void k_buildE(const float* __restrict__ emb, unsigned short* __restrict__ E) {
    int t = threadIdx.x;
    int row = blockIdx.x * 4 + (t >> 6);
    int e4 = (t & 63) * 4;
    float4 v = *(const float4*)&emb[(size_t)row * 256 + e4];
    ushort4 hi, lo;
    hi.x = f2bf_rn(v.x); lo.x = f2bf_rn(v.x - bf2f(hi.x));
    hi.y = f2bf_rn(v.y); lo.y = f2bf_rn(v.y - bf2f(hi.y));
    hi.z = f2bf_rn(v.z); lo.z = f2bf_rn(v.z - bf2f(hi.z));
    hi.w = f2bf_rn(v.w); lo.w = f2bf_rn(v.w - bf2f(hi.w));
    size_t base = (size_t)row * 768;
    *(ushort4*)&E[base + e4] = hi;
    *(ushort4*)&E[base + 256 + e4] = lo;
    *(ushort4*)&E[base + 512 + e4] = hi;
}

// ---------------------------------------------------------------------------
// MLP GEMM on split-bf16 MFMA, 128x128 tiles, r3 2-barrier K-loop (12 kc).
// GELU=1 (mlp1, A=E' codes, B=W1s dims): out Hs[krow][768] = split(gelu(h)),
//   stores are 32B-coalesced runs (krow = MFMA row side -> no scatter).
// GELU=0 (mlp2, A=W2s dims, B=Hs codes): out C_t[drow][8192] = h.
// ---------------------------------------------------------------------------
template <int GELU>
__global__ __launch_bounds__(256) void k_mlp(const unsigned short* __restrict__ A,
                                             const unsigned short* __restrict__ B,
                                             unsigned short* __restrict__ Hs,
                                             float* __restrict__ C_t) {
    __shared__ __align__(16) char smem[32768];
    unsigned short* Asm = (unsigned short*)smem;
    unsigned short* Bsm = (unsigned short*)(smem + 16384);

    int t = threadIdx.x;
    int lane = t & 63;
    int w = t >> 6;
    int wm = w >> 1, wn = w & 1;
    int m0 = blockIdx.y * 128;
    int n0 = blockIdx.x * 128;

    int rA = w * 8 + (lane >> 3);
    int ch_l = lane & 7;
    int ch_g = ch_l ^ (lane >> 3);
    const unsigned short* gA = A + (size_t)(m0 + rA) * 768 + ch_g * 8;
    const unsigned short* gB = B + (size_t)(n0 + rA) * 768 + ch_g * 8;
    unsigned short* lA = &Asm[rA * 64 + ch_l * 8];
    unsigned short* lB = &Bsm[rA * 64 + ch_l * 8];

    f32x4 acc[4][4];
#pragma unroll
    for (int i = 0; i < 4; ++i)
#pragma unroll
        for (int j = 0; j < 4; ++j)
            acc[i][j] = f32x4{0.f, 0.f, 0.f, 0.f};

#pragma unroll
    for (int i = 0; i < 4; ++i) {
        gl2lds16(gA + (size_t)(32 * i) * 768, lA + 32 * i * 64);
        gl2lds16(gB + (size_t)(32 * i) * 768, lB + 32 * i * 64);
    }
    __syncthreads();

    int l15 = lane & 15;
    int quad = lane >> 4;
    int sw = l15 & 7;
    for (int kc = 0; kc < 12; ++kc) {
#pragma unroll
        for (int kk = 0; kk < 2; ++kk) {
            short8 a[4], b[4];
#pragma unroll
            for (int i = 0; i < 4; ++i)
                a[i] = *(const short8*)&Asm[(wm * 64 + i * 16 + l15) * 64 +
                                            (((kk * 4 + quad) ^ sw) * 8)];
#pragma unroll
            for (int j = 0; j < 4; ++j)
                b[j] = *(const short8*)&Bsm[(wn * 64 + j * 16 + l15) * 64 +
                                            (((kk * 4 + quad) ^ sw) * 8)];
#pragma unroll
            for (int i = 0; i < 4; ++i)
#pragma unroll
                for (int j = 0; j < 4; ++j)
                    acc[i][j] = __builtin_amdgcn_mfma_f32_16x16x32_bf16(a[i], b[j], acc[i][j], 0, 0, 0);
        }
        __syncthreads();
        if (kc < 11) {
            int ko = (kc + 1) * 64;
#pragma unroll
            for (int i = 0; i < 4; ++i) {
                gl2lds16(gA + (size_t)(32 * i) * 768 + ko, lA + 32 * i * 64);
                gl2lds16(gB + (size_t)(32 * i) * 768 + ko, lB + 32 * i * 64);
            }
            __syncthreads();
        }
    }

    // epilogue: C/D layout col=lane&15, row=quad*4+reg
#pragma unroll
    for (int i = 0; i < 4; ++i) {
#pragma unroll
        for (int reg = 0; reg < 4; ++reg) {
            int mrow = m0 + wm * 64 + i * 16 + quad * 4 + reg;
#pragma unroll
            for (int j = 0; j < 4; ++j) {
                int ncol = n0 + wn * 64 + j * 16 + l15;
                float h = acc[i][j][reg];
                if (GELU) {
                    // mrow = code k, ncol = dim d; consecutive l15 -> contiguous
                    float g = 0.5f * h * (1.f + erff(h * 0.70710678118654752f));
                    unsigned short hb = f2bf_rn(g);
                    unsigned short lb = f2bf_rn(g - bf2f(hb));
                    size_t base = (size_t)mrow * 768;
                    Hs[base + ncol] = hb;
                    Hs[base + 256 + ncol] = lb;
                    Hs[base + 512 + ncol] = hb;
                } else {
                    C_t[(size_t)mrow * 8192 + ncol] = h;
                }
            }
        }
    }
}

// ---------------------------------------------------------------------------
// buildB: C_t [256][8192] -> Bhi/Blo [KCB][256]; csq, sC, sCl; per-128-tile
// maxima of sC/sCl; global maxima into accums[3]/[4]; per-dim partial sums.
// ---------------------------------------------------------------------------
__global__ void k_buildB(const float* __restrict__ C_t,
                         unsigned short* __restrict__ Bhi,
                         unsigned short* __restrict__ Blo,
                         float* __restrict__ csq,
                         float* __restrict__ sC, float* __restrict__ sCl,
                         unsigned* __restrict__ tileMaxC, unsigned* __restrict__ tileMaxCl,
                         float* __restrict__ accums, float* __restrict__ partialC) {
    __shared__ ushort2 tile[64][65];
    __shared__ float kacc[64];
    __shared__ float lacc[64];
    __shared__ float pc[256];
    int t = threadIdx.x;
    int k0 = blockIdx.x * 64;
    if (t < 64) { kacc[t] = 0.f; lacc[t] = 0.f; }
    pc[t] = 0.f;
    __syncthreads();
    int nn_r = t & 63, dg = t >> 6;
    float a1 = 0.f, a2 = 0.f;
    for (int dc = 0; dc < 256; dc += 64) {
        for (int r = 0; r < 16; ++r) {
            int dd = r * 4 + dg;
            float v = C_t[(size_t)(dc + dd) * KCB + k0 + nn_r];
            unsigned short hb = f2bf_rn(v);
            float hf = bf2f(hb);
            unsigned short lb = f2bf_rn(v - hf);
            float lf = bf2f(lb);
            tile[dd][nn_r] = make_ushort2(hb, lb);
            a1 += v * v;
            a2 += lf * lf;
        }
        __syncthreads();
        int kk = t & 63, ng = t >> 6;
        float dimsum = 0.f;
        for (int i2 = 0; i2 < 16; ++i2) {
            int nn = ng + i2 * 4;
            ushort2 hl = tile[kk][nn];
            size_t base = (size_t)(k0 + nn) * 256;
            Bhi[base + dc + kk] = hl.x;
            Blo[base + dc + kk] = hl.y;
            dimsum += bf2f(hl.x) + bf2f(hl.y);
        }
        atomicAdd(&pc[dc + kk], dimsum);
        __syncthreads();
    }
    atomicAdd(&kacc[nn_r], a1);
    atomicAdd(&lacc[nn_r], a2);
    __syncthreads();
    if (t < 64) {
        float c2 = kacc[t], l2 = lacc[t];
        float sc = sqrtf(c2), sl = sqrtf(l2);
        csq[k0 + t] = c2;
        sC[k0 + t] = sc;
        sCl[k0 + t] = sl;
        int tl = blockIdx.x >> 1;
        atomicMax(&tileMaxC[tl], __float_as_uint(sc));
        atomicMax(&tileMaxCl[tl], __float_as_uint(sl));
        atomicMax((unsigned*)&accums[3], __float_as_uint(c2));
        atomicMax((unsigned*)&accums[4], __float_as_uint(l2));
    }
    partialC[blockIdx.x * 256 + t] = pc[t];
}

// ---------------------------------------------------------------------------
// Phase-1: d_hi GEMM, BM=256 x BN=128, 512 threads (8 waves), BK=64, 4 kc.
// Value-only row-min (packed's k-field is never read downstream; packed2 is
// built by rescore). Slim 2-pass epilogue + LDS-staged candidate appends.
// LDS 48 KB.
// ---------------------------------------------------------------------------
__global__ __launch_bounds__(512) void k_dist_hi(const unsigned short* __restrict__ A,
                                                 const unsigned short* __restrict__ B,
                                                 const float* __restrict__ zsq,
                                                 const float* __restrict__ csq,
                                                 const float* __restrict__ sA,
                                                 const float* __restrict__ sB,
                                                 const unsigned* __restrict__ tileMaxC,
                                                 const unsigned* __restrict__ tileMaxCl,
                                                 unsigned long long* __restrict__ packed,
                                                 float* __restrict__ accums,
                                                 unsigned long long* __restrict__ cand) {
    __shared__ __align__(16) char smem[49152];
    unsigned short* Asm = (unsigned short*)smem;            // [256][64] 32 KB
    unsigned short* Bsm = (unsigned short*)(smem + 32768);  // [128][64] 16 KB
    // epilogue aliases (valid only after the final K-loop barrier):
    float* sbd     = (float*)smem;                   // [2][256]  0..2048
    float* gprev_s = (float*)(smem + 2048);          // [256]
    float* thr     = (float*)(smem + 3072);          // [256]
    unsigned* scnt  = (unsigned*)(smem + 4096);
    unsigned* sbase = (unsigned*)(smem + 4100);
    unsigned long long* scand = (unsigned long long*)(smem + 4112); // [SCAP]

    int t = threadIdx.x;
    int lane = t & 63;
    int w = t >> 6;                 // 0..7
    int wm = w >> 1, wn = w & 1;    // wm 0..3, wn 0..1
    int m0 = blockIdx.x * 256;
    int n0 = blockIdx.y * 128;

    int rA0 = w * 8 + (lane >> 3);  // 0..63
    int ch_l = lane & 7;
    int ch_g = ch_l ^ (lane >> 3);
    const unsigned short* gA = A + (size_t)(m0 + rA0) * 256 + ch_g * 8;
    const unsigned short* gB = B + (size_t)(n0 + rA0) * 256 + ch_g * 8;
    unsigned short* lA = &Asm[rA0 * 64 + ch_l * 8];
    unsigned short* lB = &Bsm[rA0 * 64 + ch_l * 8];

    int l15 = lane & 15;
    int quad = lane >> 4;
    int sw = l15 & 7;

    // hoisted epilogue constants
    float M1 = sqrtf(accums[3]);
    float M2 = sqrtf(accums[4]);
    float msC  = __uint_as_float(tileMaxC[blockIdx.y]);
    float msCl = __uint_as_float(tileMaxCl[blockIdx.y]);
    float cv[4];
    int cols[4];
#pragma unroll
    for (int j = 0; j < 4; ++j) {
        int cloc = wn * 64 + j * 16 + l15;
        cols[j] = n0 + cloc;
        cv[j] = csq[cols[j]];
    }

    f32x4 acc[4][4];
#pragma unroll
    for (int i = 0; i < 4; ++i)
#pragma unroll
        for (int j = 0; j < 4; ++j)
            acc[i][j] = f32x4{0.f, 0.f, 0.f, 0.f};

    // prologue: stage kc=0 (A: 4 row-groups of 64, B: 2)
#pragma unroll
    for (int i = 0; i < 4; ++i)
        gl2lds16(gA + (size_t)(64 * i) * 256, lA + 64 * i * 64);
#pragma unroll
    for (int i = 0; i < 2; ++i)
        gl2lds16(gB + (size_t)(64 * i) * 256, lB + 64 * i * 64);
    __syncthreads();

    for (int kc = 0; kc < 4; ++kc) {
#pragma unroll
        for (int kk = 0; kk < 2; ++kk) {
            short8 a[4], b[4];
#pragma unroll
            for (int i = 0; i < 4; ++i)
                a[i] = *(const short8*)&Asm[(wm * 64 + i * 16 + l15) * 64 +
                                            (((kk * 4 + quad) ^ sw) * 8)];
#pragma unroll
            for (int j = 0; j < 4; ++j)
                b[j] = *(const short8*)&Bsm[(wn * 64 + j * 16 + l15) * 64 +
                                            (((kk * 4 + quad) ^ sw) * 8)];
#pragma unroll
            for (int i = 0; i < 4; ++i)
#pragma unroll
                for (int j = 0; j < 4; ++j)
                    acc[i][j] = __builtin_amdgcn_mfma_f32_16x16x32_bf16(a[i], b[j], acc[i][j], 0, 0, 0);
        }
        __syncthreads();
        if (kc < 3) {
            int ko = (kc + 1) * 64;
#pragma unroll
            for (int i = 0; i < 4; ++i)
                gl2lds16(gA + (size_t)(64 * i) * 256 + ko, lA + 64 * i * 64);
#pragma unroll
            for (int i = 0; i < 2; ++i)
                gl2lds16(gB + (size_t)(64 * i) * 256 + ko, lB + 64 * i * 64);
            __syncthreads();
        }
    }

    // ---- pass 1: transform in place + value-only per-row min
    if (t == 0) *scnt = 0;
    if (t < 256) {
        const unsigned* hp = (const unsigned*)&packed[m0 + t];
        gprev_s[t] = __uint_as_float(__atomic_load_n(hp + 1, __ATOMIC_RELAXED));
    }
#pragma unroll
    for (int i = 0; i < 4; ++i) {
#pragma unroll
        for (int reg = 0; reg < 4; ++reg) {
            int rloc = wm * 64 + i * 16 + quad * 4 + reg;
            float zs = zsq[m0 + rloc];
            float d0 = (zs + cv[0]) - 2.0f * acc[i][0][reg];
            float d1 = (zs + cv[1]) - 2.0f * acc[i][1][reg];
            float d2 = (zs + cv[2]) - 2.0f * acc[i][2][reg];
            float d3 = (zs + cv[3]) - 2.0f * acc[i][3][reg];
            acc[i][0][reg] = d0; acc[i][1][reg] = d1;
            acc[i][2][reg] = d2; acc[i][3][reg] = d3;
            float bd = fminf(fminf(d0, d1), fminf(d2, d3));
#pragma unroll
            for (int off = 1; off < 16; off <<= 1)
                bd = fminf(bd, __shfl_xor(bd, off, 64));
            if (l15 == 0) sbd[wn * 256 + rloc] = bd;
        }
    }
    __syncthreads();
    // ---- t<256: merge halves, global min (fire-and-forget), row threshold
    if (t < 256) {
        float bd = fminf(sbd[t], sbd[256 + t]);
        atomicMin(&packed[m0 + t], (unsigned long long)__float_as_uint(bd) << 32);
        float g = fminf(bd, gprev_s[t]);
        thr[t] = g + 1e-3f + sA[m0 + t] * (M1 + msC) + sB[m0 + t] * (M2 + msCl);
    }
    __syncthreads();
    // ---- pass 2: 1-compare filter + staged appends
    unsigned* cnt = (unsigned*)&accums[2];
#pragma unroll
    for (int i = 0; i < 4; ++i) {
#pragma unroll
        for (int reg = 0; reg < 4; ++reg) {
            int rloc = wm * 64 + i * 16 + quad * 4 + reg;
            float tr = thr[rloc];
            bool p0 = acc[i][0][reg] <= tr;
            bool p1 = acc[i][1][reg] <= tr;
            bool p2 = acc[i][2][reg] <= tr;
            bool p3 = acc[i][3][reg] <= tr;
            if (__ballot(p0 | p1 | p2 | p3)) {
                unsigned rbits = (unsigned)((m0 + rloc) << 13);
#pragma unroll
                for (int j = 0; j < 4; ++j) {
                    bool p = (j == 0) ? p0 : (j == 1) ? p1 : (j == 2) ? p2 : p3;
                    if (p) {
                        unsigned long long entry =
                            ((unsigned long long)__float_as_uint(acc[i][j][reg]) << 32) |
                            (rbits | (unsigned)cols[j]);
                        unsigned pos = atomicAdd(scnt, 1u);
                        if (pos < SCAP) scand[pos] = entry;
                        else {
                            unsigned gp2 = atomicAdd(cnt, 1u);
                            if (gp2 < CAP) cand[gp2] = entry;
                        }
                    }
                }
            }
        }
    }
    __syncthreads();
    if (t == 0) {
        unsigned m = *scnt;
        if (m > SCAP) m = SCAP;
        *scnt = m;
        *sbase = atomicAdd(cnt, m);
    }
    __syncthreads();
    {
        unsigned m = *scnt, b0 = *sbase;
        for (unsigned u = t; u < m; u += 512)
            if (b0 + u < CAP) cand[b0 + u] = scand[u];
    }
}

// ---------------------------------------------------------------------------
// Phase-2: re-filter vs final row min, exact rescore, lex atomicMin
// ---------------------------------------------------------------------------
__global__ __launch_bounds__(256) void k_rescore(const unsigned long long* __restrict__ cand,
                                                 const unsigned short* __restrict__ Ahi,
                                                 const unsigned short* __restrict__ Alo,
                                                 const unsigned short* __restrict__ Bhi,
                                                 const unsigned short* __restrict__ Blo,
                                                 const float* __restrict__ zsq,
                                                 const float* __restrict__ csq,
                                                 const float* __restrict__ sA,
                                                 const float* __restrict__ sB,
                                                 const float* __restrict__ sC,
                                                 const float* __restrict__ sCl,
                                                 const unsigned long long* __restrict__ packed,
                                                 unsigned long long* __restrict__ packed2,
                                                 const float* __restrict__ accums) {
    unsigned total = *(const unsigned*)&accums[2];
    if (total > CAP) total = CAP;
    float M1 = sqrtf(accums[3]);
    float M2 = sqrtf(accums[4]);
    int lane = threadIdx.x & 63;
    unsigned wv = blockIdx.x * 4 + (threadIdx.x >> 6);
    unsigned nw = gridDim.x * 4;
    for (unsigned e = wv; e < total; e += nw) {
        unsigned long long ent = cand[e];
        float dhi = __uint_as_float((unsigned)(ent >> 32));
        unsigned nk = (unsigned)ent;
        int n = (nk >> 13) & 16383;
        int k = nk & 8191;
        float g = __uint_as_float((unsigned)(packed[n] >> 32));
        float marg = g + 1e-3f + sA[n] * (M1 + sC[k]) + sB[n] * (M2 + sCl[k]);
        if (dhi > marg) continue;
        ushort4 zh = *((const ushort4*)(Ahi + (size_t)n * 256) + lane);
        ushort4 zl = *((const ushort4*)(Alo + (size_t)n * 256) + lane);
        ushort4 ch = *((const ushort4*)(Bhi + (size_t)k * 256) + lane);
        ushort4 cl = *((const ushort4*)(Blo + (size_t)k * 256) + lane);
        float s = (bf2f(zh.x) + bf2f(zl.x)) * (bf2f(ch.x) + bf2f(cl.x))
                + (bf2f(zh.y) + bf2f(zl.y)) * (bf2f(ch.y) + bf2f(cl.y))
                + (bf2f(zh.z) + bf2f(zl.z)) * (bf2f(ch.z) + bf2f(cl.z))
                + (bf2f(zh.w) + bf2f(zl.w)) * (bf2f(ch.w) + bf2f(cl.w));
#pragma unroll
        for (int off = 1; off < 64; off <<= 1)
            s += __shfl_xor(s, off, 64);
        if (lane == 0) {
            float dd = (zsq[n] + csq[k]) - 2.0f * s;
            unsigned long long p =
                ((unsigned long long)__float_as_uint(dd) << 32) | (unsigned)k;
            atomicMin(&packed2[n], p);
        }
    }
}

__global__ void k_unpack(const unsigned long long* __restrict__ packed2,
                         int* __restrict__ idx, int* __restrict__ counts) {
    int n = blockIdx.x * 256 + threadIdx.x;
    unsigned long long p = packed2[n];
    int k = (int)(p & 0xffffffffull);
    idx[n] = k;
    atomicAdd(&counts[k], 1);
}

__global__ void k_zqloss(const float* __restrict__ z, const float* __restrict__ C_t,
                         const int* __restrict__ idx, float* __restrict__ out,
                         float* __restrict__ loss_sum) {
    __shared__ float red[256];
    int bid = blockIdx.x;
    int b = bid >> 8;
    int d = bid & 255;
    int t = threadIdx.x;
    const float* crow = C_t + (size_t)d * KCB;
    const int* ib = idx + b * THW;
    size_t base = ((size_t)(b * DIM + d)) * THW;
    float lsum = 0.f;
    for (int it = 0; it < 32; ++it) {
        int thw = it * 256 + t;
        int id = ib[thw];
        float v = crow[id];
        float zz = z[base + thw];
        out[base + thw] = v;
        float df = v - zz;
        lsum += df * df;
    }
    red[t] = lsum;
    __syncthreads();
    for (int s = 128; s > 0; s >>= 1) {
        if (t < s) red[t] += red[t + s];
        __syncthreads();
    }
    if (t == 0) atomicAdd(loss_sum, red[0]);
}

// ---------------------------------------------------------------------------
// Final scalars: loss, perplexity, closed-form mean_distance
// ---------------------------------------------------------------------------
__global__ void k_scalars(const int* __restrict__ counts,
                          const float* __restrict__ accums,
                          const float* __restrict__ zsq, const float* __restrict__ csq,
                          const float* __restrict__ partialZ,
                          const float* __restrict__ partialC,
                          float* __restrict__ out_tail) {
    __shared__ double redd[256];
    __shared__ float redf[256];
    int t = threadIdx.x;
    double szsq = 0.0, scsq = 0.0;
    for (int n = t; n < NTOK; n += 256) szsq += (double)zsq[n];
    for (int k = t; k < KCB; k += 256) scsq += (double)csq[k];
    float SZ = 0.f, SC = 0.f;
    for (int b2 = 0; b2 < 256; ++b2) SZ += partialZ[b2 * 256 + t];
    for (int b2 = 0; b2 < 128; ++b2) SC += partialC[b2 * 256 + t];
    double total = 8192.0 * szsq + 16384.0 * scsq - 2.0 * (double)SZ * (double)SC;
    redd[t] = total;
    float s = 0.f;
    for (int k = t; k < KCB; k += 256) {
        float e = (float)counts[k] * (1.0f / 16384.0f);
        s += e * logf(e + 1e-10f);
    }
    redf[t] = s;
    __syncthreads();
    for (int st = 128; st > 0; st >>= 1) {
        if (t < st) { redd[t] += redd[t + st]; redf[t] += redf[t + st]; }
        __syncthreads();
    }
    if (t == 0) {
        out_tail[0] = 1.25f * accums[1] / 4194304.0f;
        out_tail[1] = expf(-redf[0]);
        out_tail[2] = (float)(redd[0] / (16384.0 * 8192.0));
    }
}

// ---------------------------------------------------------------------------
extern "C" void kernel_launch(void* const* d_in, const int* in_sizes, int n_in,
                              void* d_out, int out_size, void* d_ws, size_t ws_size,
                              hipStream_t stream) {
    const float* z     = (const float*)d_in[0];   // [2][256][8192]
    const float* emb_w = (const float*)d_in[1];   // [8192][256]
    const float* w1    = (const float*)d_in[2];   // [256][256]
    const float* w2    = (const float*)d_in[3];   // [256][256]
    float* out = (float*)d_out;

    char* w = (char*)d_ws;
    unsigned short* Ahi = (unsigned short*)(w + 0);          //  8,388,608
    unsigned short* Alo = (unsigned short*)(w + 8388608);    //  8,388,608
    unsigned short* Ebf = (unsigned short*)(w + 16777216);   // 12,582,912 (E'; C_t aliases after mlp1)
    unsigned short* Bhi = (unsigned short*)(w + 29360128);   //  4,194,304
    unsigned short* Blo = (unsigned short*)(w + 33554432);   //  4,194,304
    unsigned short* W1s = (unsigned short*)(w + 37748736);   //    393,216
    unsigned short* W2s = (unsigned short*)(w + 38141952);   //    393,216
    float* zsq   = (float*)(w + 38535168);   // 65,536
    float* sA    = (float*)(w + 38666240);   // 65,536
    float* sB    = (float*)(w + 38731776);   // 65,536
    float* csq   = (float*)(w + 38797312);   // 32,768
    float* sC    = (float*)(w + 38862848);   // 32,768
    float* sCl   = (float*)(w + 38895616);   // 32,768
    unsigned long long* packed  = (unsigned long long*)(w + 38928384); // 131,072
    unsigned long long* packed2 = (unsigned long long*)(w + 39059456); // 131,072
    int*   idx    = (int*)(w + 39190528);    // 65,536
    int*   counts = (int*)(w + 39256064);    // 32,768
    float* partialZ = (float*)(w + 39288832); // 262,144
    float* partialC = (float*)(w + 39550976); // 131,072
    unsigned* tileMaxC  = (unsigned*)(w + 39682048); // 256
    unsigned* tileMaxCl = (unsigned*)(w + 39682304); // 256
    float* accums = (float*)(w + 39682560);  // [1]loss [2]cnt [3]csqmax [4]closqmax

    float* C_t = (float*)Ebf;                        // alias: E' dead after mlp1
    unsigned short* Hs = (unsigned short*)d_out;     // Hs then cand share d_out
    unsigned long long* cand = (unsigned long long*)d_out;

    hipMemsetAsync(counts, 0, 32768, stream);
    hipMemsetAsync(tileMaxC, 0, 1024, stream);       // tileMax* + accums
    hipMemsetAsync(packed, 0xFF, 262144, stream);    // packed + packed2

    k_buildA<<<NTOK / 64, 256, 0, stream>>>(z, Ahi, Alo, zsq, sA, sB, partialZ);
    k_splitW<<<512, 256, 0, stream>>>(w1, w2, W1s, W2s);
    k_buildE<<<KCB / 4, 256, 0, stream>>>(emb_w, Ebf);

    // MLP: Hs[k][768] = split(gelu(E' x W1s^T))  (codes on the M side)
    k_mlp<1><<<dim3(2, KCB / 128), 256, 0, stream>>>(Ebf, W1s, Hs, nullptr);
    // C_t[d][8192] = W2s x Hs^T
    k_mlp<0><<<dim3(KCB / 128, 2), 256, 0, stream>>>(W2s, Hs, nullptr, C_t);

    k_buildB<<<KCB / 64, 256, 0, stream>>>(C_t, Bhi, Blo, csq, sC, sCl,
                                           tileMaxC, tileMaxCl, accums, partialC);

    // Phase-1: d_hi GEMM (256x128 tiles) + row-min + candidate append
    k_dist_hi<<<dim3(NTOK / 256, KCB / 128), 512, 0, stream>>>(
        Ahi, Bhi, zsq, csq, sA, sB, tileMaxC, tileMaxCl, packed, accums, cand);

    // Phase-2: exact rescore of survivors
    k_rescore<<<1024, 256, 0, stream>>>(cand, Ahi, Alo, Bhi, Blo, zsq, csq,
                                        sA, sB, sC, sCl, packed, packed2, accums);

    k_unpack<<<NTOK / 256, 256, 0, stream>>>(packed2, idx, counts);
    k_zqloss<<<BATCH * DIM, 256, 0, stream>>>(z, C_t, idx, out, accums + 1);
    k_scalars<<<1, 256, 0, stream>>>(counts, accums, zsq, csq, partialZ, partialC, out + OUTQ);
}